// Round 7
// baseline (184.310 us; speedup 1.0000x reference)
//
// RoutingFreeGate — v7: barrier-free MFMA K-loop. A direct from f32 x (cvt in
// reg), B direct from L2-resident bf16 Wb, no LDS / no __syncthreads in the
// K-loop -> loads pipeline across K-steps (v6 stalled on the barrier's
// vmcnt(0) drain every step). BM=64 halves B L2 traffic vs v6.
#include <hip/hip_runtime.h>
#include <hip/hip_bf16.h>
#include <math.h>

#define H_DIM 2048
#define R_DIM 512
#define NTOK  16384
#define BM    64
#define BK    64
#define KSTEPS (H_DIM / BK)          // 32
#define NEG_BIG (-1.0e30f)           // finite in f32 AND after bf16 rounding

typedef __attribute__((ext_vector_type(8))) short bf16x8;
typedef __attribute__((ext_vector_type(4))) float f32x4;

static __device__ __forceinline__ unsigned short f2bf(float f) {
    __hip_bfloat16 h = __float2bfloat16(f);   // RNE
    return *reinterpret_cast<unsigned short*>(&h);
}

static __device__ __forceinline__ bf16x8 pack8(float4 lo, float4 hi) {
    union { bf16x8 v; unsigned short u[8]; } t;
    t.u[0] = f2bf(lo.x); t.u[1] = f2bf(lo.y); t.u[2] = f2bf(lo.z); t.u[3] = f2bf(lo.w);
    t.u[4] = f2bf(hi.x); t.u[5] = f2bf(hi.y); t.u[6] = f2bf(hi.z); t.u[7] = f2bf(hi.w);
    return t.v;
}

// ---------------------------------------------------------------------------
// W (512x2048 f32) -> bf16 in d_ws.
// ---------------------------------------------------------------------------
__global__ __launch_bounds__(256) void rfg7_wcvt(
    const float* __restrict__ W, unsigned short* __restrict__ Wb)
{
    const int i = (blockIdx.x * 256 + threadIdx.x) * 8;
    float4 a = *reinterpret_cast<const float4*>(W + i);
    float4 b = *reinterpret_cast<const float4*>(W + i + 4);
    *reinterpret_cast<bf16x8*>(Wb + i) = pack8(a, b);
}

// ---------------------------------------------------------------------------
// Block: 64 rows x 512 cols, 8 waves as 2(row)x4(col) of 32x128 wave-tiles.
// mfma_f32_16x16x32_bf16; C/D: col=l&15, row=(l>>4)*4+reg [m89/m91].
// Mask applied at epilogue (masked rows -> hidden=0, norm=0); K-loop is pure
// load+cvt+MFMA, barrier-free.
// ---------------------------------------------------------------------------
__global__ __launch_bounds__(512, 2) void rfg7_gemm(
    const float* __restrict__ x,
    const unsigned char* __restrict__ msk,
    const unsigned short* __restrict__ Wb,
    const float* __restrict__ gsc,
    const float* __restrict__ gbi,
    float* __restrict__ om,
    float* __restrict__ os,
    float* __restrict__ hid)
{
    __shared__ float Ps[4][BM];          // [wc][row] norm partials

    const int tid = threadIdx.x;
    const int w   = tid >> 6;            // 0..7
    const int l   = tid & 63;
    const int wr  = w >> 2;              // row-group 0..1 (32 rows each)
    const int wc  = w & 3;               // col-group 0..3 (128 cols each)
    const int fr  = l & 15;
    const int fg  = l >> 4;              // k-subgroup 0..3
    const int m0  = blockIdx.x * BM;

    // A: lane loads rows m0+wr*32+mi*16+fr, k = ks*64 + kk*32 + fg*8 (8 f32)
    const float* xA0 = x + (size_t)(m0 + wr * 32 + fr) * H_DIM + fg * 8;
    const float* xA1 = xA0 + 16 * H_DIM;
    // B: lane loads W rows (=C cols) wc*128+ni*16+fr, same k layout (bf16)
    const unsigned short* wb = Wb + (size_t)(wc * 128 + fr) * H_DIM + fg * 8;

    f32x4 acc[2][8] = {};

    #pragma unroll 2
    for (int ks = 0; ks < KSTEPS; ++ks) {
        const int ko = ks * BK;

        bf16x8 bfr[2][8];
        #pragma unroll
        for (int kk = 0; kk < 2; ++kk)
            #pragma unroll
            for (int ni = 0; ni < 8; ++ni)
                bfr[kk][ni] = *reinterpret_cast<const bf16x8*>(
                    wb + (size_t)ni * (16 * H_DIM) + ko + kk * 32);

        bf16x8 afr[2][2];
        #pragma unroll
        for (int mi = 0; mi < 2; ++mi)
            #pragma unroll
            for (int kk = 0; kk < 2; ++kk) {
                const float* ap = (mi ? xA1 : xA0) + ko + kk * 32;
                float4 lo = *reinterpret_cast<const float4*>(ap);
                float4 hi = *reinterpret_cast<const float4*>(ap + 4);
                afr[mi][kk] = pack8(lo, hi);
            }

        #pragma unroll
        for (int kk = 0; kk < 2; ++kk)
            #pragma unroll
            for (int mi = 0; mi < 2; ++mi)
                #pragma unroll
                for (int ni = 0; ni < 8; ++ni)
                    acc[mi][ni] = __builtin_amdgcn_mfma_f32_16x16x32_bf16(
                        afr[mi][kk], bfr[kk][ni], acc[mi][ni], 0, 0, 0);
    }

    // ---- epilogue: apply row mask, norm partials, C write ----
    float mr[2][4];
    #pragma unroll
    for (int mi = 0; mi < 2; ++mi)
        #pragma unroll
        for (int r = 0; r < 4; ++r)
            mr[mi][r] = msk[m0 + wr * 32 + mi * 16 + fg * 4 + r] ? 1.0f : 0.0f;

    #pragma unroll
    for (int mi = 0; mi < 2; ++mi)
        #pragma unroll
        for (int ni = 0; ni < 8; ++ni)
            #pragma unroll
            for (int r = 0; r < 4; ++r)
                acc[mi][ni][r] *= mr[mi][r];

    #pragma unroll
    for (int mi = 0; mi < 2; ++mi) {
        #pragma unroll
        for (int r = 0; r < 4; ++r) {
            float s = 0.0f;
            #pragma unroll
            for (int ni = 0; ni < 8; ++ni) {
                const float v = acc[mi][ni][r];
                s = fmaf(v, v, s);
            }
            #pragma unroll
            for (int off = 1; off < 16; off <<= 1)
                s += __shfl_xor(s, off, 64);
            if (fr == 0) Ps[wc][wr * 32 + mi * 16 + fg * 4 + r] = s;
        }
    }

    #pragma unroll
    for (int mi = 0; mi < 2; ++mi)
        #pragma unroll
        for (int ni = 0; ni < 8; ++ni)
            #pragma unroll
            for (int r = 0; r < 4; ++r) {
                const int row = m0 + wr * 32 + mi * 16 + fg * 4 + r;
                hid[(size_t)row * R_DIM + wc * 128 + ni * 16 + fr] = acc[mi][ni][r];
            }

    __syncthreads();
    if (tid < BM) {
        const float s = Ps[0][tid] + Ps[1][tid] + Ps[2][tid] + Ps[3][tid];
        float sc = sqrtf(s) * gsc[0] - gbi[0];
        if (!(sc > -1.0e30f && sc < 1.0e30f)) sc = 0.0f;  // never emit inf/nan
        const bool keep = (msk[m0 + tid] != 0) && (sc >= 0.5f);
        om[m0 + tid] = keep ? 1.0f : 0.0f;
        os[m0 + tid] = keep ? sc : NEG_BIG;
    }
}

extern "C" void kernel_launch(void* const* d_in, const int* in_sizes, int n_in,
                              void* d_out, int out_size, void* d_ws, size_t ws_size,
                              hipStream_t stream)
{
    const float*         x     = (const float*)d_in[0];
    const unsigned char* msk   = (const unsigned char*)d_in[1];  // jax bool = 1B
    const float*         W     = (const float*)d_in[2];
    const float*         scale = (const float*)d_in[3];
    const float*         bias  = (const float*)d_in[4];

    float* out = (float*)d_out;
    float* om  = out;               // [NTOK]
    float* os  = out + NTOK;        // [NTOK]
    float* hid = out + 2 * NTOK;    // [NTOK][R_DIM]

    unsigned short* Wb = (unsigned short*)d_ws;  // 2 MiB bf16 W

    rfg7_wcvt<<<(R_DIM * H_DIM / 8) / 256, 256, 0, stream>>>(W, Wb);
    rfg7_gemm<<<NTOK / BM, 512, 0, stream>>>(x, msk, Wb, scale, bias, om, os, hid);
}

// Round 8
// 155.958 us; speedup vs baseline: 1.1818x; 1.1818x over previous
//
// RoutingFreeGate — v8: T3 minimal 2-phase LDS pipeline. v7 failed because
// hipcc serialized per-register global loads (VGPR=72 proves no pipelining).
// Fix: global_load_lds staging (fire-and-forget, no VGPRs), double-buffered,
// one barrier per K-step. BN=256 split; norm finished by tiny score kernel
// using om/os as cross-block partial-sum scratch.
#include <hip/hip_runtime.h>
#include <hip/hip_bf16.h>
#include <math.h>

#define H_DIM 2048
#define R_DIM 512
#define NTOK  16384
#define BMT   64
#define BNT   256
#define BKT   32
#define KST   (H_DIM / BKT)          // 64
#define NEG_BIG (-1.0e30f)           // finite in f32 AND after bf16 rounding

typedef __attribute__((ext_vector_type(8))) short bf16x8;
typedef __attribute__((ext_vector_type(4))) float f32x4;

static __device__ __forceinline__ unsigned short f2bf(float f) {
    __hip_bfloat16 h = __float2bfloat16(f);   // RNE
    return *reinterpret_cast<unsigned short*>(&h);
}

static __device__ __forceinline__ bf16x8 pack8(float4 lo, float4 hi) {
    union { bf16x8 v; unsigned short u[8]; } t;
    t.u[0] = f2bf(lo.x); t.u[1] = f2bf(lo.y); t.u[2] = f2bf(lo.z); t.u[3] = f2bf(lo.w);
    t.u[4] = f2bf(hi.x); t.u[5] = f2bf(hi.y); t.u[6] = f2bf(hi.z); t.u[7] = f2bf(hi.w);
    return t.v;
}

static __device__ __forceinline__ void gll16(const void* g, void* l) {
    __builtin_amdgcn_global_load_lds(
        (const __attribute__((address_space(1))) unsigned int*)g,
        (__attribute__((address_space(3))) unsigned int*)l,
        16, 0, 0);
}

// ---------------------------------------------------------------------------
// W (512x2048 f32) -> bf16 in d_ws.
// ---------------------------------------------------------------------------
__global__ __launch_bounds__(256) void rfg8_wcvt(
    const float* __restrict__ W, unsigned short* __restrict__ Wb)
{
    const int i = (blockIdx.x * 256 + threadIdx.x) * 8;
    float4 a = *reinterpret_cast<const float4*>(W + i);
    float4 b = *reinterpret_cast<const float4*>(W + i + 4);
    *reinterpret_cast<bf16x8*>(Wb + i) = pack8(a, b);
}

// ---------------------------------------------------------------------------
// GEMM tile: 64 rows x 256 cols, 8 waves as 2(row)x4(col) of 32x64.
// K-loop: STAGE(next) -> ds_read -> pack -> 8 MFMA -> barrier (T3 2-phase).
// LDS k-chunk-major layouts give bank-quad = fr&7 (conflict-free b128).
// Mask applied to acc at epilogue. Row-norm partial written to p[row].
// ---------------------------------------------------------------------------
__global__ __launch_bounds__(512, 4) void rfg8_gemm(
    const float* __restrict__ x,
    const unsigned char* __restrict__ msk,
    const unsigned short* __restrict__ Wb,
    float* __restrict__ p0,              // partial sumsq, n-tile 0 (om slot)
    float* __restrict__ p1,              // partial sumsq, n-tile 1 (os slot)
    float* __restrict__ hid)
{
    __shared__ float4 As[2][8][64];                  // [buf][h=k/4][row] 16 KiB
    __shared__ __align__(16) short Bs[2][4][256][8]; // [buf][k8][col][8]  32 KiB
    __shared__ float Ps[4][BMT];

    const int tid = threadIdx.x;
    const int mt  = blockIdx.x >> 1;
    const int nt  = blockIdx.x & 1;
    const int m0  = mt * BMT;
    const int n0  = nt * BNT;

    const int w  = tid >> 6;
    const int l  = tid & 63;
    const int wr = w >> 2;               // 0..1: 32-row group
    const int wc = w & 3;                // 0..3: 64-col group
    const int fr = l & 15;
    const int fg = l >> 4;

    // ---- staging sources (per-thread, +k0 per step) ----
    const float* gA = x + (size_t)(m0 + (tid & 63)) * H_DIM + ((tid >> 6) << 2);
    const unsigned short* gB0 = Wb + (size_t)(n0 + (tid & 255)) * H_DIM + ((tid >> 8) << 3);
    const unsigned short* gB1 = Wb + (size_t)(n0 + ((512 + tid) & 255)) * H_DIM + (((512 + tid) >> 8) << 3);
    // ---- staging dests (linear: chunk idx == issue order) ----
    char* const ldsA = (char*)&As[0][0][0] + tid * 16;            // +buf*8192
    char* const ldsB = (char*)&Bs[0][0][0][0] + tid * 16;         // +buf*16384 (+512*16 for j=1)

    f32x4 acc[2][4] = {};

#define RFG8_STAGE(buf, ks) do {                                   \
        const int _k0 = (ks) * BKT;                                \
        gll16(gA + _k0,  ldsA + (buf) * 8192);                     \
        gll16(gB0 + _k0, ldsB + (buf) * 16384);                    \
        gll16(gB1 + _k0, ldsB + (buf) * 16384 + 8192);             \
    } while (0)

    RFG8_STAGE(0, 0);
    __syncthreads();

    for (int ks = 0; ks < KST; ++ks) {
        const int buf = ks & 1;
        if (ks + 1 < KST) RFG8_STAGE(buf ^ 1, ks + 1);

        bf16x8 bfr[4];
        #pragma unroll
        for (int ni = 0; ni < 4; ++ni)
            bfr[ni] = *reinterpret_cast<const bf16x8*>(
                &Bs[buf][fg][wc * 64 + ni * 16 + fr][0]);

        bf16x8 afr[2];
        #pragma unroll
        for (int mi = 0; mi < 2; ++mi) {
            const int row = wr * 32 + mi * 16 + fr;
            float4 lo = As[buf][2 * fg][row];
            float4 hi = As[buf][2 * fg + 1][row];
            afr[mi] = pack8(lo, hi);
        }

        #pragma unroll
        for (int mi = 0; mi < 2; ++mi)
            #pragma unroll
            for (int ni = 0; ni < 4; ++ni)
                acc[mi][ni] = __builtin_amdgcn_mfma_f32_16x16x32_bf16(
                    afr[mi], bfr[ni], acc[mi][ni], 0, 0, 0);

        __syncthreads();
    }
#undef RFG8_STAGE

    // ---- epilogue: mask rows, norm partials, C write ----
    float mr[2][4];
    #pragma unroll
    for (int mi = 0; mi < 2; ++mi)
        #pragma unroll
        for (int r = 0; r < 4; ++r)
            mr[mi][r] = msk[m0 + wr * 32 + mi * 16 + fg * 4 + r] ? 1.0f : 0.0f;

    #pragma unroll
    for (int mi = 0; mi < 2; ++mi)
        #pragma unroll
        for (int ni = 0; ni < 4; ++ni)
            #pragma unroll
            for (int r = 0; r < 4; ++r)
                acc[mi][ni][r] *= mr[mi][r];

    #pragma unroll
    for (int mi = 0; mi < 2; ++mi) {
        #pragma unroll
        for (int r = 0; r < 4; ++r) {
            float s = 0.0f;
            #pragma unroll
            for (int ni = 0; ni < 4; ++ni) {
                const float v = acc[mi][ni][r];
                s = fmaf(v, v, s);
            }
            #pragma unroll
            for (int off = 1; off < 16; off <<= 1)
                s += __shfl_xor(s, off, 64);
            if (fr == 0) Ps[wc][wr * 32 + mi * 16 + fg * 4 + r] = s;
        }
    }

    #pragma unroll
    for (int mi = 0; mi < 2; ++mi)
        #pragma unroll
        for (int ni = 0; ni < 4; ++ni)
            #pragma unroll
            for (int r = 0; r < 4; ++r) {
                const int row = m0 + wr * 32 + mi * 16 + fg * 4 + r;
                hid[(size_t)row * R_DIM + n0 + wc * 64 + ni * 16 + fr] =
                    acc[mi][ni][r];
            }

    __syncthreads();
    if (tid < BMT) {
        const float s = Ps[0][tid] + Ps[1][tid] + Ps[2][tid] + Ps[3][tid];
        (nt ? p1 : p0)[m0 + tid] = s;   // cross-block partial in om/os slot
    }
}

// ---------------------------------------------------------------------------
// Finish: combine the two n-tile partials, sqrt/scale/bias, gate, overwrite.
// ---------------------------------------------------------------------------
__global__ __launch_bounds__(256) void rfg8_score(
    const unsigned char* __restrict__ msk,
    const float* __restrict__ gsc,
    const float* __restrict__ gbi,
    float* __restrict__ om,
    float* __restrict__ os)
{
    const int t = blockIdx.x * 256 + threadIdx.x;
    const float s = om[t] + os[t];
    float sc = sqrtf(s) * gsc[0] - gbi[0];
    if (!(sc > -1.0e30f && sc < 1.0e30f)) sc = 0.0f;  // never emit inf/nan
    const bool keep = (msk[t] != 0) && (sc >= 0.5f);
    om[t] = keep ? 1.0f : 0.0f;
    os[t] = keep ? sc : NEG_BIG;
}

extern "C" void kernel_launch(void* const* d_in, const int* in_sizes, int n_in,
                              void* d_out, int out_size, void* d_ws, size_t ws_size,
                              hipStream_t stream)
{
    const float*         x     = (const float*)d_in[0];
    const unsigned char* msk   = (const unsigned char*)d_in[1];  // jax bool = 1B
    const float*         W     = (const float*)d_in[2];
    const float*         scale = (const float*)d_in[3];
    const float*         bias  = (const float*)d_in[4];

    float* out = (float*)d_out;
    float* om  = out;               // [NTOK]
    float* os  = out + NTOK;        // [NTOK]
    float* hid = out + 2 * NTOK;    // [NTOK][R_DIM]

    unsigned short* Wb = (unsigned short*)d_ws;  // 2 MiB bf16 W

    rfg8_wcvt<<<(R_DIM * H_DIM / 8) / 256, 256, 0, stream>>>(W, Wb);
    rfg8_gemm<<<(NTOK / BMT) * 2, 512, 0, stream>>>(x, msk, Wb, om, os, hid);
    rfg8_score<<<NTOK / 256, 256, 0, stream>>>(msk, scale, bias, om, os);
}

// Round 9
// 155.848 us; speedup vs baseline: 1.1826x; 1.0007x over previous
//
// RoutingFreeGate — v9: 2-phase with m97-class amortization. v8's 8 MFMA per
// barrier x 64 barriers made the per-step vmcnt-drain dominate (MfmaUtil 7%).
// Now: BK=64, 16 MFMA/wave/step, 32 steps, 64x128 tile, 2 blocks/CU, XCD-
// swizzle so each m-panel's 4 n-tiles share one XCD's L2 (A read once/XCD).
#include <hip/hip_runtime.h>
#include <hip/hip_bf16.h>
#include <math.h>

#define H_DIM 2048
#define R_DIM 512
#define NTOK  16384
#define BM    64
#define BN    128
#define BK    64
#define KST   (H_DIM / BK)           // 32
#define NEG_BIG (-1.0e30f)           // finite in f32 AND after bf16 rounding

typedef __attribute__((ext_vector_type(8))) short bf16x8;
typedef __attribute__((ext_vector_type(4))) float f32x4;

static __device__ __forceinline__ unsigned short f2bf(float f) {
    __hip_bfloat16 h = __float2bfloat16(f);   // RNE
    return *reinterpret_cast<unsigned short*>(&h);
}

static __device__ __forceinline__ bf16x8 pack8(float4 lo, float4 hi) {
    union { bf16x8 v; unsigned short u[8]; } t;
    t.u[0] = f2bf(lo.x); t.u[1] = f2bf(lo.y); t.u[2] = f2bf(lo.z); t.u[3] = f2bf(lo.w);
    t.u[4] = f2bf(hi.x); t.u[5] = f2bf(hi.y); t.u[6] = f2bf(hi.z); t.u[7] = f2bf(hi.w);
    return t.v;
}

static __device__ __forceinline__ void gll16(const void* g, void* l) {
    __builtin_amdgcn_global_load_lds(
        (const __attribute__((address_space(1))) unsigned int*)g,
        (__attribute__((address_space(3))) unsigned int*)l,
        16, 0, 0);
}

// ---------------------------------------------------------------------------
// W (512x2048 f32) -> bf16 in d_ws.
// ---------------------------------------------------------------------------
__global__ __launch_bounds__(256) void rfg9_wcvt(
    const float* __restrict__ W, unsigned short* __restrict__ Wb)
{
    const int i = (blockIdx.x * 256 + threadIdx.x) * 8;
    float4 a = *reinterpret_cast<const float4*>(W + i);
    float4 b = *reinterpret_cast<const float4*>(W + i + 4);
    *reinterpret_cast<bf16x8*>(Wb + i) = pack8(a, b);
}

// ---------------------------------------------------------------------------
// GEMM tile 64x128, 256 thr / 4 waves (2 row-groups x 2 col-groups of 32x64).
// Per K-step: 8 gload_lds (A f32 16K + B bf16 16K, dbuf) -> 16 ds_read_b128
// -> 4 pack8 -> 16 MFMA -> one barrier. A packed f32->bf16 in-reg (VALU pipe
// overlaps MFMA across waves). Mask/norm in epilogue.
// ---------------------------------------------------------------------------
__global__ __launch_bounds__(256) void rfg9_gemm(
    const float* __restrict__ x,
    const unsigned char* __restrict__ msk,
    const unsigned short* __restrict__ Wb,
    float* __restrict__ part,            // [4][NTOK] cross-block sumsq partials
    float* __restrict__ hid)
{
    __shared__ float4 As[2][16][64];                 // [buf][k/4][row]   2x16K
    __shared__ __align__(16) short Bs[2][8][128][8]; // [buf][k/8][col][8] 2x16K
    __shared__ float Ps[2][BM];

    const int tid = threadIdx.x;
    // XCD swizzle: 4 n-tiles of one m-panel -> same XCD (A L2-reuse x4).
    const int bid   = blockIdx.x;
    const int xcd   = bid & 7;
    const int local = bid >> 3;
    const int nt    = local & 3;
    const int mt    = ((local >> 2) << 3) | xcd;     // bijective, mt 0..255
    const int m0    = mt * BM;
    const int n0    = nt * BN;

    const int w  = tid >> 6;
    const int l  = tid & 63;
    const int wr = w >> 1;               // 0..1: 32-row group
    const int wc = w & 1;                // 0..1: 64-col group
    const int fr = l & 15;
    const int fg = l >> 4;

    // staging sources: A chunk (j*4 + (t>>6), t&63); B chunk (j*2+(t>>7), t&127)
    const float* gA = x + (size_t)(m0 + (tid & 63)) * H_DIM + ((tid >> 6) << 2);
    const unsigned short* gB = Wb + (size_t)(n0 + (tid & 127)) * H_DIM + ((tid >> 7) << 3);
    char* const ldsA = (char*)&As[0][0][0] + tid * 16;     // +buf*16384, +j*4096
    char* const ldsB = (char*)&Bs[0][0][0][0] + tid * 16;

    f32x4 acc[2][4] = {};

#define RFG9_STAGE(buf, ks) do {                                     \
        const int _k0 = (ks) * BK;                                   \
        gll16(gA + _k0,      ldsA + (buf) * 16384);                  \
        gll16(gA + _k0 + 16, ldsA + (buf) * 16384 + 4096);           \
        gll16(gA + _k0 + 32, ldsA + (buf) * 16384 + 8192);           \
        gll16(gA + _k0 + 48, ldsA + (buf) * 16384 + 12288);          \
        gll16(gB + _k0,      ldsB + (buf) * 16384);                  \
        gll16(gB + _k0 + 16, ldsB + (buf) * 16384 + 4096);           \
        gll16(gB + _k0 + 32, ldsB + (buf) * 16384 + 8192);           \
        gll16(gB + _k0 + 48, ldsB + (buf) * 16384 + 12288);          \
    } while (0)

    RFG9_STAGE(0, 0);
    __syncthreads();

    for (int ks = 0; ks < KST; ++ks) {
        const int buf = ks & 1;
        if (ks + 1 < KST) RFG9_STAGE(buf ^ 1, ks + 1);

        bf16x8 bfr[2][4];
        #pragma unroll
        for (int kk = 0; kk < 2; ++kk)
            #pragma unroll
            for (int ni = 0; ni < 4; ++ni)
                bfr[kk][ni] = *reinterpret_cast<const bf16x8*>(
                    &Bs[buf][kk * 4 + fg][wc * 64 + ni * 16 + fr][0]);

        bf16x8 afr[2][2];
        #pragma unroll
        for (int mi = 0; mi < 2; ++mi)
            #pragma unroll
            for (int kk = 0; kk < 2; ++kk) {
                const int row = wr * 32 + mi * 16 + fr;
                float4 lo = As[buf][kk * 8 + fg * 2][row];
                float4 hi = As[buf][kk * 8 + fg * 2 + 1][row];
                afr[mi][kk] = pack8(lo, hi);
            }

        #pragma unroll
        for (int kk = 0; kk < 2; ++kk)
            #pragma unroll
            for (int mi = 0; mi < 2; ++mi)
                #pragma unroll
                for (int ni = 0; ni < 4; ++ni)
                    acc[mi][ni] = __builtin_amdgcn_mfma_f32_16x16x32_bf16(
                        afr[mi][kk], bfr[kk][ni], acc[mi][ni], 0, 0, 0);

        __syncthreads();
    }
#undef RFG9_STAGE

    // ---- epilogue: mask rows, norm partials, C write ----
    float mr[2][4];
    #pragma unroll
    for (int mi = 0; mi < 2; ++mi)
        #pragma unroll
        for (int r = 0; r < 4; ++r)
            mr[mi][r] = msk[m0 + wr * 32 + mi * 16 + fg * 4 + r] ? 1.0f : 0.0f;

    #pragma unroll
    for (int mi = 0; mi < 2; ++mi)
        #pragma unroll
        for (int ni = 0; ni < 4; ++ni)
            #pragma unroll
            for (int r = 0; r < 4; ++r)
                acc[mi][ni][r] *= mr[mi][r];

    #pragma unroll
    for (int mi = 0; mi < 2; ++mi) {
        #pragma unroll
        for (int r = 0; r < 4; ++r) {
            float s = 0.0f;
            #pragma unroll
            for (int ni = 0; ni < 4; ++ni) {
                const float v = acc[mi][ni][r];
                s = fmaf(v, v, s);
            }
            #pragma unroll
            for (int off = 1; off < 16; off <<= 1)
                s += __shfl_xor(s, off, 64);
            if (fr == 0) Ps[wc][wr * 32 + mi * 16 + fg * 4 + r] = s;
        }
    }

    #pragma unroll
    for (int mi = 0; mi < 2; ++mi)
        #pragma unroll
        for (int ni = 0; ni < 4; ++ni)
            #pragma unroll
            for (int r = 0; r < 4; ++r) {
                const int row = m0 + wr * 32 + mi * 16 + fg * 4 + r;
                hid[(size_t)row * R_DIM + n0 + wc * 64 + ni * 16 + fr] =
                    acc[mi][ni][r];
            }

    __syncthreads();
    if (tid < BM)
        part[(size_t)nt * NTOK + m0 + tid] = Ps[0][tid] + Ps[1][tid];
}

// ---------------------------------------------------------------------------
// Finish: sum 4 n-tile partials, sqrt/scale/bias, gate.
// ---------------------------------------------------------------------------
__global__ __launch_bounds__(256) void rfg9_score(
    const unsigned char* __restrict__ msk,
    const float* __restrict__ gsc,
    const float* __restrict__ gbi,
    const float* __restrict__ part,
    float* __restrict__ om,
    float* __restrict__ os)
{
    const int t = blockIdx.x * 256 + threadIdx.x;
    const float s = part[t] + part[NTOK + t] + part[2 * NTOK + t] + part[3 * NTOK + t];
    float sc = sqrtf(s) * gsc[0] - gbi[0];
    if (!(sc > -1.0e30f && sc < 1.0e30f)) sc = 0.0f;  // never emit inf/nan
    const bool keep = (msk[t] != 0) && (sc >= 0.5f);
    om[t] = keep ? 1.0f : 0.0f;
    os[t] = keep ? sc : NEG_BIG;
}

extern "C" void kernel_launch(void* const* d_in, const int* in_sizes, int n_in,
                              void* d_out, int out_size, void* d_ws, size_t ws_size,
                              hipStream_t stream)
{
    const float*         x     = (const float*)d_in[0];
    const unsigned char* msk   = (const unsigned char*)d_in[1];  // jax bool = 1B
    const float*         W     = (const float*)d_in[2];
    const float*         scale = (const float*)d_in[3];
    const float*         bias  = (const float*)d_in[4];

    float* out = (float*)d_out;
    float* om  = out;               // [NTOK]
    float* os  = out + NTOK;        // [NTOK]
    float* hid = out + 2 * NTOK;    // [NTOK][R_DIM]

    unsigned short* Wb   = (unsigned short*)d_ws;                 // 2 MiB
    float*          part = (float*)((char*)d_ws + 2 * 1024 * 1024); // 256 KiB

    rfg9_wcvt<<<(R_DIM * H_DIM / 8) / 256, 256, 0, stream>>>(W, Wb);
    rfg9_gemm<<<(NTOK / BM) * (R_DIM / BN), 256, 0, stream>>>(x, msk, Wb, part, hid);
    rfg9_score<<<NTOK / 256, 256, 0, stream>>>(msk, scale, bias, part, om, os);
}

// Round 10
// 113.663 us; speedup vs baseline: 1.6216x; 1.3711x over previous
//
// RoutingFreeGate — v10: counted-vmcnt 3-buffer pipeline (T3+T4+T5).
// v6-v9 all hit ~3700 cy/K-step: __syncthreads' vmcnt(0) drain exposes full
// HBM latency every step. Now: s_waitcnt vmcnt(4) -> raw s_barrier ->
// sched_barrier(0) -> stage(k+2) -> ds_read/pack/16 MFMA in setprio(1).
// 3 LDS buffers make stage-vs-read races structurally impossible.
#include <hip/hip_runtime.h>
#include <hip/hip_bf16.h>
#include <math.h>

#define H_DIM 2048
#define R_DIM 512
#define NTOK  16384
#define BM    128
#define BN    256
#define BK    32
#define KST   (H_DIM / BK)           // 64
#define NEG_BIG (-1.0e30f)           // finite in f32 AND after bf16 rounding

typedef __attribute__((ext_vector_type(8))) short bf16x8;
typedef __attribute__((ext_vector_type(4))) float f32x4;

static __device__ __forceinline__ unsigned short f2bf(float f) {
    __hip_bfloat16 h = __float2bfloat16(f);   // RNE
    return *reinterpret_cast<unsigned short*>(&h);
}

static __device__ __forceinline__ bf16x8 pack8(float4 lo, float4 hi) {
    union { bf16x8 v; unsigned short u[8]; } t;
    t.u[0] = f2bf(lo.x); t.u[1] = f2bf(lo.y); t.u[2] = f2bf(lo.z); t.u[3] = f2bf(lo.w);
    t.u[4] = f2bf(hi.x); t.u[5] = f2bf(hi.y); t.u[6] = f2bf(hi.z); t.u[7] = f2bf(hi.w);
    return t.v;
}

static __device__ __forceinline__ void gll16(const void* g, void* l) {
    __builtin_amdgcn_global_load_lds(
        (const __attribute__((address_space(1))) unsigned int*)g,
        (__attribute__((address_space(3))) unsigned int*)l,
        16, 0, 0);
}

// ---------------------------------------------------------------------------
// W (512x2048 f32) -> bf16 in d_ws.
// ---------------------------------------------------------------------------
__global__ __launch_bounds__(256) void rfg10_wcvt(
    const float* __restrict__ W, unsigned short* __restrict__ Wb)
{
    const int i = (blockIdx.x * 256 + threadIdx.x) * 8;
    float4 a = *reinterpret_cast<const float4*>(W + i);
    float4 b = *reinterpret_cast<const float4*>(W + i + 4);
    *reinterpret_cast<bf16x8*>(Wb + i) = pack8(a, b);
}

// ---------------------------------------------------------------------------
// GEMM tile 128x256, 512 thr / 8 waves (4 row-groups x 2 col-groups; wave
// tile 32x128). Per K-step: vmcnt(4) -> s_barrier -> sched_barrier ->
// stage(k+2) [4 gload_lds] -> 12 ds_read_b128 -> 2 pack8 -> 16 MFMA.
// LDS: 3 bufs x (A 16K f32 + B 16K bf16) = 96 KiB, k-chunk-major (2-way free).
// ---------------------------------------------------------------------------
__global__ __launch_bounds__(512, 2) void rfg10_gemm(
    const float* __restrict__ x,
    const unsigned char* __restrict__ msk,
    const unsigned short* __restrict__ Wb,
    float* __restrict__ part,            // [2][NTOK] cross-block sumsq partials
    float* __restrict__ hid)
{
    __shared__ __align__(16) float4 As[3][8][128];   // [buf][k4][row]  3x16K
    __shared__ __align__(16) short Bs[3][4][256][8]; // [buf][k8][col][8] 3x16K
    __shared__ float Ps[2][BM];

    const int tid = threadIdx.x;
    // XCD swizzle: the 2 n-tiles of an m-panel land on the same XCD.
    const int bid   = blockIdx.x;            // 256 blocks
    const int xcd   = bid & 7;
    const int local = bid >> 3;              // 0..31
    const int nt    = local & 1;
    const int mt    = (local >> 1) * 8 + xcd;  // bijective 0..127
    const int m0    = mt * BM;
    const int n0    = nt * BN;

    const int w  = tid >> 6;
    const int l  = tid & 63;
    const int wr = w >> 1;               // 0..3: 32-row group
    const int wc = w & 1;                // 0..1: 128-col group
    const int fr = l & 15;
    const int fg = l >> 4;

    // staging sources (chunk t and t+512 of each 1024-chunk buffer)
    const float* gA = x + (size_t)(m0 + (tid & 127)) * H_DIM + ((tid >> 7) << 2);
    const unsigned short* gB = Wb + (size_t)(n0 + (tid & 255)) * H_DIM + ((tid >> 8) << 3);
    char* const ldsA = (char*)&As[0][0][0] + tid * 16;      // +buf*16384, +8192
    char* const ldsB = (char*)&Bs[0][0][0][0] + tid * 16;

    f32x4 acc[2][8] = {};

#define RFG10_STAGE(ks_, buf_) do {                                  \
        const int _k0 = (ks_) * BK;                                  \
        gll16(gA + _k0,      ldsA + (buf_) * 16384);                 \
        gll16(gA + _k0 + 16, ldsA + (buf_) * 16384 + 8192);          \
        gll16(gB + _k0,      ldsB + (buf_) * 16384);                 \
        gll16(gB + _k0 + 16, ldsB + (buf_) * 16384 + 8192);          \
    } while (0)

#define RFG10_STEP(ks_, buf_, last_) do {                            \
        if (last_) asm volatile("s_waitcnt vmcnt(0)" ::: "memory");  \
        else       asm volatile("s_waitcnt vmcnt(4)" ::: "memory");  \
        __builtin_amdgcn_s_barrier();                                \
        __builtin_amdgcn_sched_barrier(0);                           \
        if ((ks_) + 2 < KST) RFG10_STAGE((ks_) + 2, ((ks_) + 2) % 3);\
        bf16x8 bfr[8];                                               \
        _Pragma("unroll")                                            \
        for (int ni = 0; ni < 8; ++ni)                               \
            bfr[ni] = *reinterpret_cast<const bf16x8*>(              \
                &Bs[buf_][fg][wc * 128 + ni * 16 + fr][0]);          \
        bf16x8 afr[2];                                               \
        _Pragma("unroll")                                            \
        for (int mi = 0; mi < 2; ++mi) {                             \
            const int row = wr * 32 + mi * 16 + fr;                  \
            float4 lo = As[buf_][fg * 2][row];                       \
            float4 hi = As[buf_][fg * 2 + 1][row];                   \
            afr[mi] = pack8(lo, hi);                                 \
        }                                                            \
        __builtin_amdgcn_s_setprio(1);                               \
        _Pragma("unroll")                                            \
        for (int mi = 0; mi < 2; ++mi)                               \
            _Pragma("unroll")                                        \
            for (int ni = 0; ni < 8; ++ni)                           \
                acc[mi][ni] = __builtin_amdgcn_mfma_f32_16x16x32_bf16(\
                    afr[mi], bfr[ni], acc[mi][ni], 0, 0, 0);         \
        __builtin_amdgcn_s_setprio(0);                               \
    } while (0)

    RFG10_STAGE(0, 0);
    RFG10_STAGE(1, 1);

    for (int kb = 0; kb < KST - 1; kb += 3) {   // 0,3,...,60 -> steps 0..62
        RFG10_STEP(kb,     0, false);
        RFG10_STEP(kb + 1, 1, false);
        RFG10_STEP(kb + 2, 2, false);
    }
    RFG10_STEP(KST - 1, 0, true);               // step 63, buf 63%3==0

#undef RFG10_STEP
#undef RFG10_STAGE

    // ---- epilogue: mask rows, norm partials, C write ----
    float mr[2][4];
    #pragma unroll
    for (int mi = 0; mi < 2; ++mi)
        #pragma unroll
        for (int r = 0; r < 4; ++r)
            mr[mi][r] = msk[m0 + wr * 32 + mi * 16 + fg * 4 + r] ? 1.0f : 0.0f;

    #pragma unroll
    for (int mi = 0; mi < 2; ++mi)
        #pragma unroll
        for (int ni = 0; ni < 8; ++ni)
            #pragma unroll
            for (int r = 0; r < 4; ++r)
                acc[mi][ni][r] *= mr[mi][r];

    #pragma unroll
    for (int mi = 0; mi < 2; ++mi) {
        #pragma unroll
        for (int r = 0; r < 4; ++r) {
            float s = 0.0f;
            #pragma unroll
            for (int ni = 0; ni < 8; ++ni) {
                const float v = acc[mi][ni][r];
                s = fmaf(v, v, s);
            }
            #pragma unroll
            for (int off = 1; off < 16; off <<= 1)
                s += __shfl_xor(s, off, 64);
            if (fr == 0) Ps[wc][wr * 32 + mi * 16 + fg * 4 + r] = s;
        }
    }

    #pragma unroll
    for (int mi = 0; mi < 2; ++mi)
        #pragma unroll
        for (int ni = 0; ni < 8; ++ni)
            #pragma unroll
            for (int r = 0; r < 4; ++r) {
                const int row = m0 + wr * 32 + mi * 16 + fg * 4 + r;
                hid[(size_t)row * R_DIM + n0 + wc * 128 + ni * 16 + fr] =
                    acc[mi][ni][r];
            }

    __syncthreads();
    if (tid < BM)
        part[(size_t)nt * NTOK + m0 + tid] = Ps[0][tid] + Ps[1][tid];
}

// ---------------------------------------------------------------------------
// Finish: sum the 2 n-tile partials, sqrt/scale/bias, gate.
// ---------------------------------------------------------------------------
__global__ __launch_bounds__(256) void rfg10_score(
    const unsigned char* __restrict__ msk,
    const float* __restrict__ gsc,
    const float* __restrict__ gbi,
    const float* __restrict__ part,
    float* __restrict__ om,
    float* __restrict__ os)
{
    const int t = blockIdx.x * 256 + threadIdx.x;
    const float s = part[t] + part[NTOK + t];
    float sc = sqrtf(s) * gsc[0] - gbi[0];
    if (!(sc > -1.0e30f && sc < 1.0e30f)) sc = 0.0f;  // never emit inf/nan
    const bool keep = (msk[t] != 0) && (sc >= 0.5f);
    om[t] = keep ? 1.0f : 0.0f;
    os[t] = keep ? sc : NEG_BIG;
}

extern "C" void kernel_launch(void* const* d_in, const int* in_sizes, int n_in,
                              void* d_out, int out_size, void* d_ws, size_t ws_size,
                              hipStream_t stream)
{
    const float*         x     = (const float*)d_in[0];
    const unsigned char* msk   = (const unsigned char*)d_in[1];  // jax bool = 1B
    const float*         W     = (const float*)d_in[2];
    const float*         scale = (const float*)d_in[3];
    const float*         bias  = (const float*)d_in[4];

    float* out = (float*)d_out;
    float* om  = out;               // [NTOK]
    float* os  = out + NTOK;        // [NTOK]
    float* hid = out + 2 * NTOK;    // [NTOK][R_DIM]

    unsigned short* Wb   = (unsigned short*)d_ws;                   // 2 MiB
    float*          part = (float*)((char*)d_ws + 2 * 1024 * 1024); // 128 KiB

    rfg10_wcvt<<<(R_DIM * H_DIM / 8) / 256, 256, 0, stream>>>(W, Wb);
    rfg10_gemm<<<(NTOK / BM) * (R_DIM / BN), 512, 0, stream>>>(x, msk, Wb, part, hid);
    rfg10_score<<<NTOK / 256, 256, 0, stream>>>(msk, scale, bias, part, om, os);
}

// Round 11
// 87.084 us; speedup vs baseline: 2.1165x; 1.3052x over previous
//
// RoutingFreeGate — v11: m97-clone (proven 874-TF structure). 128x128 tile,
// BK=32, 48 KiB LDS -> 3 blocks/CU resident; cross-block overlap covers the
// barrier drain (v10 had 1 block/CU -> fully exposed stalls). B re-laid
// K-major in wcvt for contiguous staging; A staged f32 with rule-#21 swizzle
// (linear LDS dest + inverse-swizzled global src + swizzled ds_read).
#include <hip/hip_runtime.h>
#include <hip/hip_bf16.h>
#include <math.h>

#define H_DIM 2048
#define R_DIM 512
#define NTOK  16384
#define BM    128
#define BN    128
#define BK    32
#define KST   (H_DIM / BK)           // 64
#define NEG_BIG (-1.0e30f)           // finite in f32 AND after bf16 rounding

typedef __attribute__((ext_vector_type(8))) short bf16x8;
typedef __attribute__((ext_vector_type(4))) float f32x4;

static __device__ __forceinline__ unsigned short f2bf(float f) {
    __hip_bfloat16 h = __float2bfloat16(f);   // RNE
    return *reinterpret_cast<unsigned short*>(&h);
}

static __device__ __forceinline__ bf16x8 pack8(float4 lo, float4 hi) {
    union { bf16x8 v; unsigned short u[8]; } t;
    t.u[0] = f2bf(lo.x); t.u[1] = f2bf(lo.y); t.u[2] = f2bf(lo.z); t.u[3] = f2bf(lo.w);
    t.u[4] = f2bf(hi.x); t.u[5] = f2bf(hi.y); t.u[6] = f2bf(hi.z); t.u[7] = f2bf(hi.w);
    return t.v;
}

static __device__ __forceinline__ void gll16(const void* g, void* l) {
    __builtin_amdgcn_global_load_lds(
        (const __attribute__((address_space(1))) unsigned int*)g,
        (__attribute__((address_space(3))) unsigned int*)l,
        16, 0, 0);
}

// ---------------------------------------------------------------------------
// W (512x2048 f32, row-major) -> bf16 K-major: Wb[(k>>3)*512 + r][8] so a
// (k8-slab, 128-col) B stage is contiguous 2 KiB per slab.
// ---------------------------------------------------------------------------
__global__ __launch_bounds__(256) void rfg11_wcvt(
    const float* __restrict__ W, unsigned short* __restrict__ Wb)
{
    const int i  = blockIdx.x * 256 + threadIdx.x;   // 0..131071
    const int r  = i >> 8;                           // 0..511
    const int k8 = i & 255;                          // 0..255
    const float* src = W + (size_t)r * H_DIM + k8 * 8;
    float4 a = *reinterpret_cast<const float4*>(src);
    float4 b = *reinterpret_cast<const float4*>(src + 4);
    *reinterpret_cast<bf16x8*>(Wb + ((size_t)k8 * R_DIM + r) * 8) = pack8(a, b);
}

// ---------------------------------------------------------------------------
// GEMM 128x128, BK=32, 256 thr / 4 waves (2x2 of 64x64), acc[4][4],
// 16 MFMA/wave/step, plain dbuf + __syncthreads (m97 structure).
// A in LDS as f32 [128 row][8 chunk16B], source-swizzled: LDS[row][c] holds
// x chunk c^(row&7) -> ds_read at chunk (2fg)^(row&7) is conflict-free.
// B in LDS [k8][col][8] bf16 from K-major Wb (contiguous staging).
// ---------------------------------------------------------------------------
__global__ __launch_bounds__(256, 3) void rfg11_gemm(
    const float* __restrict__ x,
    const unsigned char* __restrict__ msk,
    const unsigned short* __restrict__ Wb,
    float* __restrict__ part,            // [4][NTOK] cross-block sumsq partials
    float* __restrict__ hid)
{
    __shared__ __align__(16) float4 As[2][1024];     // [buf][row*8+chunk] 32 KiB
    __shared__ __align__(16) short  Bs[2][512][8];   // [buf][k8*128+col]  16 KiB
    __shared__ float Ps[2][BM];

    const int tid = threadIdx.x;
    // XCD swizzle: 4 n-tiles of one m-panel -> same XCD (A L2 reuse x4).
    const int bid   = blockIdx.x;            // 512 blocks
    const int xcd   = bid & 7;
    const int local = bid >> 3;              // 0..63
    const int nt    = local & 3;
    const int mt    = (local >> 2) * 8 + xcd;  // bijective 0..127
    const int m0    = mt * BM;
    const int n0    = nt * BN;

    const int w  = tid >> 6;
    const int l  = tid & 63;
    const int wr = w >> 1;               // 0..1: 64-row group
    const int wc = w & 1;                // 0..1: 64-col group
    const int fr = l & 15;
    const int fg = l >> 4;               // k-subgroup 0..3

    f32x4 acc[4][4] = {};

#define RFG11_STAGE(ks_, buf_) do {                                      \
        const int _kA = (ks_) * BK;                                      \
        _Pragma("unroll")                                                \
        for (int j = 0; j < 4; ++j) {                                    \
            const int idx = j * 256 + tid;                               \
            const int row = idx >> 3, cL = idx & 7;                      \
            const int cG  = cL ^ (row & 7);                              \
            gll16(x + (size_t)(m0 + row) * H_DIM + _kA + cG * 4,         \
                  (char*)&As[buf_][0] + idx * 16);                       \
        }                                                                \
        _Pragma("unroll")                                                \
        for (int j = 0; j < 2; ++j) {                                    \
            const int idx = j * 256 + tid;                               \
            const int k8 = idx >> 7, col = idx & 127;                    \
            gll16(Wb + ((size_t)((ks_) * 4 + k8) * R_DIM + n0 + col) * 8,\
                  (char*)&Bs[buf_][0][0] + idx * 16);                    \
        }                                                                \
    } while (0)

    RFG11_STAGE(0, 0);
    __syncthreads();

    for (int ks = 0; ks < KST; ++ks) {
        const int buf = ks & 1;
        if (ks + 1 < KST) RFG11_STAGE(ks + 1, buf ^ 1);

        bf16x8 bfr[4];
        #pragma unroll
        for (int ni = 0; ni < 4; ++ni)
            bfr[ni] = *reinterpret_cast<const bf16x8*>(
                &Bs[buf][fg * 128 + wc * 64 + ni * 16 + fr][0]);

        bf16x8 afr[4];
        #pragma unroll
        for (int mi = 0; mi < 4; ++mi) {
            const int row = wr * 64 + mi * 16 + fr;
            const int s   = row & 7;
            float4 lo = As[buf][row * 8 + ((2 * fg)     ^ s)];
            float4 hi = As[buf][row * 8 + ((2 * fg + 1) ^ s)];
            afr[mi] = pack8(lo, hi);
        }

        #pragma unroll
        for (int mi = 0; mi < 4; ++mi)
            #pragma unroll
            for (int ni = 0; ni < 4; ++ni)
                acc[mi][ni] = __builtin_amdgcn_mfma_f32_16x16x32_bf16(
                    afr[mi], bfr[ni], acc[mi][ni], 0, 0, 0);

        __syncthreads();
    }
#undef RFG11_STAGE

    // ---- epilogue: mask rows, norm partials, C write ----
    float mr[4][4];
    #pragma unroll
    for (int mi = 0; mi < 4; ++mi)
        #pragma unroll
        for (int r = 0; r < 4; ++r)
            mr[mi][r] = msk[m0 + wr * 64 + mi * 16 + fg * 4 + r] ? 1.0f : 0.0f;

    #pragma unroll
    for (int mi = 0; mi < 4; ++mi)
        #pragma unroll
        for (int ni = 0; ni < 4; ++ni)
            #pragma unroll
            for (int r = 0; r < 4; ++r)
                acc[mi][ni][r] *= mr[mi][r];

    #pragma unroll
    for (int mi = 0; mi < 4; ++mi) {
        #pragma unroll
        for (int r = 0; r < 4; ++r) {
            float s = 0.0f;
            #pragma unroll
            for (int ni = 0; ni < 4; ++ni) {
                const float v = acc[mi][ni][r];
                s = fmaf(v, v, s);
            }
            #pragma unroll
            for (int off = 1; off < 16; off <<= 1)
                s += __shfl_xor(s, off, 64);
            if (fr == 0) Ps[wc][wr * 64 + mi * 16 + fg * 4 + r] = s;
        }
    }

    #pragma unroll
    for (int mi = 0; mi < 4; ++mi)
        #pragma unroll
        for (int ni = 0; ni < 4; ++ni)
            #pragma unroll
            for (int r = 0; r < 4; ++r) {
                const int row = m0 + wr * 64 + mi * 16 + fg * 4 + r;
                hid[(size_t)row * R_DIM + n0 + wc * 64 + ni * 16 + fr] =
                    acc[mi][ni][r];
            }

    __syncthreads();
    if (tid < BM)
        part[(size_t)nt * NTOK + m0 + tid] = Ps[0][tid] + Ps[1][tid];
}

// ---------------------------------------------------------------------------
// Finish: sum the 4 n-tile partials, sqrt/scale/bias, gate.
// ---------------------------------------------------------------------------
__global__ __launch_bounds__(256) void rfg11_score(
    const unsigned char* __restrict__ msk,
    const float* __restrict__ gsc,
    const float* __restrict__ gbi,
    const float* __restrict__ part,
    float* __restrict__ om,
    float* __restrict__ os)
{
    const int t = blockIdx.x * 256 + threadIdx.x;
    const float s = part[t] + part[NTOK + t] + part[2 * NTOK + t] + part[3 * NTOK + t];
    float sc = sqrtf(s) * gsc[0] - gbi[0];
    if (!(sc > -1.0e30f && sc < 1.0e30f)) sc = 0.0f;  // never emit inf/nan
    const bool keep = (msk[t] != 0) && (sc >= 0.5f);
    om[t] = keep ? 1.0f : 0.0f;
    os[t] = keep ? sc : NEG_BIG;
}

extern "C" void kernel_launch(void* const* d_in, const int* in_sizes, int n_in,
                              void* d_out, int out_size, void* d_ws, size_t ws_size,
                              hipStream_t stream)
{
    const float*         x     = (const float*)d_in[0];
    const unsigned char* msk   = (const unsigned char*)d_in[1];  // jax bool = 1B
    const float*         W     = (const float*)d_in[2];
    const float*         scale = (const float*)d_in[3];
    const float*         bias  = (const float*)d_in[4];

    float* out = (float*)d_out;
    float* om  = out;               // [NTOK]
    float* os  = out + NTOK;        // [NTOK]
    float* hid = out + 2 * NTOK;    // [NTOK][R_DIM]

    unsigned short* Wb   = (unsigned short*)d_ws;                   // 2 MiB
    float*          part = (float*)((char*)d_ws + 2 * 1024 * 1024); // 256 KiB

    rfg11_wcvt<<<512, 256, 0, stream>>>(W, Wb);
    rfg11_gemm<<<(NTOK / BM) * (R_DIM / BN), 256, 0, stream>>>(x, msk, Wb, part, hid);
    rfg11_score<<<NTOK / 256, 256, 0, stream>>>(msk, scale, bias, part, om, os);
}

// Round 12
// 69.799 us; speedup vs baseline: 2.6406x; 1.2476x over previous
//
// RoutingFreeGate — v12: masked-token compaction (~50% of GEMM skipped).
// scan -> vidx[] of valid tokens (padded to 64); gemm computes only valid
// rows (BM=64, active ~516 of 1024 blocks, early-exit on nv); zero-kernel
// clears invalid hidden rows + part[]. Inner loop = v11 (proven).
#include <hip/hip_runtime.h>
#include <hip/hip_bf16.h>
#include <math.h>

#define H_DIM 2048
#define R_DIM 512
#define NTOK  16384
#define BM    64
#define BN    128
#define BK    32
#define KST   (H_DIM / BK)           // 64
#define NEG_BIG (-1.0e30f)           // finite in f32 AND after bf16 rounding

typedef __attribute__((ext_vector_type(8))) short bf16x8;
typedef __attribute__((ext_vector_type(4))) float f32x4;

static __device__ __forceinline__ unsigned short f2bf(float f) {
    __hip_bfloat16 h = __float2bfloat16(f);   // RNE
    return *reinterpret_cast<unsigned short*>(&h);
}

static __device__ __forceinline__ bf16x8 pack8(float4 lo, float4 hi) {
    union { bf16x8 v; unsigned short u[8]; } t;
    t.u[0] = f2bf(lo.x); t.u[1] = f2bf(lo.y); t.u[2] = f2bf(lo.z); t.u[3] = f2bf(lo.w);
    t.u[4] = f2bf(hi.x); t.u[5] = f2bf(hi.y); t.u[6] = f2bf(hi.z); t.u[7] = f2bf(hi.w);
    return t.v;
}

static __device__ __forceinline__ void gll16(const void* g, void* l) {
    __builtin_amdgcn_global_load_lds(
        (const __attribute__((address_space(1))) unsigned int*)g,
        (__attribute__((address_space(3))) unsigned int*)l,
        16, 0, 0);
}

// ---------------------------------------------------------------------------
// W (512x2048 f32, row-major) -> bf16 K-major Wb[(k>>3)*512 + r][8].
// ---------------------------------------------------------------------------
__global__ __launch_bounds__(256) void rfg12_wcvt(
    const float* __restrict__ W, unsigned short* __restrict__ Wb)
{
    const int i  = blockIdx.x * 256 + threadIdx.x;
    const int r  = i >> 8;
    const int k8 = i & 255;
    const float* src = W + (size_t)r * H_DIM + k8 * 8;
    float4 a = *reinterpret_cast<const float4*>(src);
    float4 b = *reinterpret_cast<const float4*>(src + 4);
    *reinterpret_cast<bf16x8*>(Wb + ((size_t)k8 * R_DIM + r) * 8) = pack8(a, b);
}

// ---------------------------------------------------------------------------
// Prefix-sum compaction: vidx[0..nv) = valid token ids (ascending), padded
// with 0 up to the next multiple of 64; nv_out[0] = nv. One 1024-thr block,
// 16 mask bytes per thread.
// ---------------------------------------------------------------------------
__global__ __launch_bounds__(1024) void rfg12_scan(
    const unsigned char* __restrict__ msk,
    int* __restrict__ vidx, int* __restrict__ nv_out)
{
    __shared__ int Wt[16];     // per-wave totals
    __shared__ int Wbase[16];  // per-wave exclusive bases
    const int tid  = threadIdx.x;
    const int lane = tid & 63;
    const int wv   = tid >> 6;

    union { uint4 v; unsigned char c[16]; } u;
    u.v = *reinterpret_cast<const uint4*>(msk + tid * 16);
    const unsigned int b = u.v.x + u.v.y + u.v.z + u.v.w;  // bytes<=4, no carry
    const int cnt = (b & 0xFF) + ((b >> 8) & 0xFF) + ((b >> 16) & 0xFF) + (b >> 24);

    int pfx = cnt;                      // wave-inclusive scan
    #pragma unroll
    for (int off = 1; off < 64; off <<= 1) {
        const int t = __shfl_up(pfx, off, 64);
        if (lane >= off) pfx += t;
    }
    if (lane == 63) Wt[wv] = pfx;
    __syncthreads();
    if (tid == 0) {
        int run = 0;
        for (int i = 0; i < 16; ++i) { Wbase[i] = run; run += Wt[i]; }
    }
    __syncthreads();

    int p = Wbase[wv] + pfx - cnt;      // exclusive start for this thread
    #pragma unroll
    for (int j = 0; j < 16; ++j)
        if (u.c[j]) vidx[p++] = tid * 16 + j;

    if (tid == 1023) {
        const int total = Wbase[15] + Wt[15];
        nv_out[0] = total;
        const int pe = (total + 63) & ~63;
        for (int i = total; i < pe; ++i) vidx[i] = 0;   // pad (never written to)
    }
}

// ---------------------------------------------------------------------------
// Zero invalid hidden rows (coalesced: 128 lanes x float4 per token) + part.
// ---------------------------------------------------------------------------
__global__ __launch_bounds__(256) void rfg12_zero(
    const unsigned char* __restrict__ msk,
    float* __restrict__ hid, float* __restrict__ part)
{
    const int b   = blockIdx.x;
    const int tid = threadIdx.x;
    part[b * 256 + tid] = 0.0f;                       // 256*256 = 4*NTOK
    const float4 z = make_float4(0.f, 0.f, 0.f, 0.f);
    #pragma unroll 4
    for (int tt = 0; tt < 32; ++tt) {
        const int t = b * 64 + tt * 2 + (tid >> 7);
        if (!msk[t])
            *reinterpret_cast<float4*>(&hid[(size_t)t * R_DIM + (tid & 127) * 4]) = z;
    }
}

// ---------------------------------------------------------------------------
// Compacted GEMM 64x128, BK=32, 256 thr / 4 waves (2x2 of 32x64), acc[2][4],
// dbuf + __syncthreads (v11 structure). A rows gathered via vidx (per-lane
// global src is legal for global_load_lds; LDS dest stays linear). C/partials
// scattered back through vidx. Blocks with m0 >= nv exit immediately.
// ---------------------------------------------------------------------------
__global__ __launch_bounds__(256, 4) void rfg12_gemm(
    const float* __restrict__ x,
    const unsigned short* __restrict__ Wb,
    const int* __restrict__ vidx,
    const int* __restrict__ nvp,
    float* __restrict__ part,            // [4][NTOK] sumsq partials
    float* __restrict__ hid)
{
    __shared__ __align__(16) float4 As[2][512];     // [buf][row*8+chunk] 16 KiB
    __shared__ __align__(16) short  Bs[2][512][8];  // [buf][k8*128+col]  16 KiB
    __shared__ float Ps[2][BM];
    __shared__ int   Vr[BM];
    __shared__ int   Vv[BM];

    const int nv  = nvp[0];
    const int tid = threadIdx.x;
    // XCD swizzle: 4 n-tiles of an m-panel -> same XCD.
    const int bid   = blockIdx.x;            // 1024 blocks
    const int xcd   = bid & 7;
    const int local = bid >> 3;              // 0..127
    const int nt    = local & 3;
    const int mt    = (local >> 2) * 8 + xcd;  // bijective 0..255
    const int m0    = mt * BM;
    if (m0 >= nv) return;
    const int n0    = nt * BN;

    const int w  = tid >> 6;
    const int l  = tid & 63;
    const int wr = w >> 1;               // 0..1: 32-row group
    const int wc = w & 1;                // 0..1: 64-col group
    const int fr = l & 15;
    const int fg = l >> 4;               // k-subgroup 0..3

    // gathered A staging rows for this thread (j=0: rows 0..31, j=1: 32..63)
    const int vr0 = vidx[m0 + (tid >> 3)];
    const int vr1 = vidx[m0 + 32 + (tid >> 3)];

    f32x4 acc[2][4] = {};

#define RFG12_STAGE(ks_, buf_) do {                                      \
        const int _kA = (ks_) * BK;                                      \
        _Pragma("unroll")                                                \
        for (int j = 0; j < 2; ++j) {                                    \
            const int idx = j * 256 + tid;                               \
            const int row = idx >> 3, cL = idx & 7;                      \
            const int cG  = cL ^ (row & 7);                              \
            gll16(x + (size_t)(j ? vr1 : vr0) * H_DIM + _kA + cG * 4,    \
                  (char*)&As[buf_][0] + idx * 16);                       \
        }                                                                \
        _Pragma("unroll")                                                \
        for (int j = 0; j < 2; ++j) {                                    \
            const int idx = j * 256 + tid;                               \
            const int k8 = idx >> 7, col = idx & 127;                    \
            gll16(Wb + ((size_t)((ks_) * 4 + k8) * R_DIM + n0 + col) * 8,\
                  (char*)&Bs[buf_][0][0] + idx * 16);                    \
        }                                                                \
    } while (0)

    RFG12_STAGE(0, 0);
    if (tid < BM) {
        Vr[tid] = vidx[m0 + tid];
        Vv[tid] = (m0 + tid) < nv;
    }
    __syncthreads();

    for (int ks = 0; ks < KST; ++ks) {
        const int buf = ks & 1;
        if (ks + 1 < KST) RFG12_STAGE(ks + 1, buf ^ 1);

        bf16x8 bfr[4];
        #pragma unroll
        for (int ni = 0; ni < 4; ++ni)
            bfr[ni] = *reinterpret_cast<const bf16x8*>(
                &Bs[buf][fg * 128 + wc * 64 + ni * 16 + fr][0]);

        bf16x8 afr[2];
        #pragma unroll
        for (int mi = 0; mi < 2; ++mi) {
            const int row = wr * 32 + mi * 16 + fr;
            const int s   = row & 7;
            float4 lo = As[buf][row * 8 + ((2 * fg)     ^ s)];
            float4 hi = As[buf][row * 8 + ((2 * fg + 1) ^ s)];
            afr[mi] = pack8(lo, hi);
        }

        #pragma unroll
        for (int mi = 0; mi < 2; ++mi)
            #pragma unroll
            for (int ni = 0; ni < 4; ++ni)
                acc[mi][ni] = __builtin_amdgcn_mfma_f32_16x16x32_bf16(
                    afr[mi], bfr[ni], acc[mi][ni], 0, 0, 0);

        __syncthreads();
    }
#undef RFG12_STAGE

    // ---- epilogue: norm partials (valid rows only), scattered C write ----
    #pragma unroll
    for (int mi = 0; mi < 2; ++mi) {
        #pragma unroll
        for (int r = 0; r < 4; ++r) {
            const int rowl = wr * 32 + mi * 16 + fg * 4 + r;
            float s = 0.0f;
            #pragma unroll
            for (int ni = 0; ni < 4; ++ni) {
                const float v = acc[mi][ni][r];
                s = fmaf(v, v, s);
            }
            #pragma unroll
            for (int off = 1; off < 16; off <<= 1)
                s += __shfl_xor(s, off, 64);
            if (fr == 0) Ps[wc][rowl] = s;
        }
    }

    #pragma unroll
    for (int mi = 0; mi < 2; ++mi)
        #pragma unroll
        for (int ni = 0; ni < 4; ++ni)
            #pragma unroll
            for (int r = 0; r < 4; ++r) {
                const int rowl = wr * 32 + mi * 16 + fg * 4 + r;
                if (Vv[rowl])
                    hid[(size_t)Vr[rowl] * R_DIM + n0 + wc * 64 + ni * 16 + fr] =
                        acc[mi][ni][r];
            }

    __syncthreads();
    if (tid < BM && Vv[tid])
        part[(size_t)nt * NTOK + Vr[tid]] = Ps[0][tid] + Ps[1][tid];
}

// ---------------------------------------------------------------------------
// Finish: sum the 4 n-tile partials, sqrt/scale/bias, gate.
// ---------------------------------------------------------------------------
__global__ __launch_bounds__(256) void rfg12_score(
    const unsigned char* __restrict__ msk,
    const float* __restrict__ gsc,
    const float* __restrict__ gbi,
    const float* __restrict__ part,
    float* __restrict__ om,
    float* __restrict__ os)
{
    const int t = blockIdx.x * 256 + threadIdx.x;
    const float s = part[t] + part[NTOK + t] + part[2 * NTOK + t] + part[3 * NTOK + t];
    float sc = sqrtf(s) * gsc[0] - gbi[0];
    if (!(sc > -1.0e30f && sc < 1.0e30f)) sc = 0.0f;  // never emit inf/nan
    const bool keep = (msk[t] != 0) && (sc >= 0.5f);
    om[t] = keep ? 1.0f : 0.0f;
    os[t] = keep ? sc : NEG_BIG;
}

extern "C" void kernel_launch(void* const* d_in, const int* in_sizes, int n_in,
                              void* d_out, int out_size, void* d_ws, size_t ws_size,
                              hipStream_t stream)
{
    const float*         x     = (const float*)d_in[0];
    const unsigned char* msk   = (const unsigned char*)d_in[1];  // jax bool = 1B
    const float*         W     = (const float*)d_in[2];
    const float*         scale = (const float*)d_in[3];
    const float*         bias  = (const float*)d_in[4];

    float* out = (float*)d_out;
    float* om  = out;               // [NTOK]
    float* os  = out + NTOK;        // [NTOK]
    float* hid = out + 2 * NTOK;    // [NTOK][R_DIM]

    char* ws = (char*)d_ws;
    unsigned short* Wb   = (unsigned short*)ws;                    // 2 MiB
    float*          part = (float*)(ws + 2 * 1024 * 1024);         // 256 KiB
    int*            vidx = (int*)(ws + 2 * 1024 * 1024 + 256 * 1024); // 64 KiB
    int*            nvp  = (int*)(ws + 2 * 1024 * 1024 + 320 * 1024); // 4 B

    rfg12_wcvt<<<512, 256, 0, stream>>>(W, Wb);
    rfg12_scan<<<1, 1024, 0, stream>>>(msk, vidx, nvp);
    rfg12_zero<<<256, 256, 0, stream>>>(msk, hid, part);
    rfg12_gemm<<<(NTOK / BM) * (R_DIM / BN), 256, 0, stream>>>(
        x, Wb, vidx, nvp, part, hid);
    rfg12_score<<<NTOK / 256, 256, 0, stream>>>(msk, scale, bias, part, om, os);
}

// Round 13
// 56.098 us; speedup vs baseline: 3.2855x; 1.2442x over previous
//
// RoutingFreeGate — v13: (a) compacted gemm with BK=64 -> 16 MFMA/wave per
// barrier (32 barriers, was 64x8-MFMA in v12); (b) wcvt+scan+zero merged into
// one aux kernel (5 launches -> 3). Inner-loop conventions proven in v11/v12.
#include <hip/hip_runtime.h>
#include <hip/hip_bf16.h>
#include <math.h>

#define H_DIM 2048
#define R_DIM 512
#define NTOK  16384
#define BM    64
#define BN    128
#define BK    64
#define KST   (H_DIM / BK)           // 32
#define NEG_BIG (-1.0e30f)           // finite in f32 AND after bf16 rounding

typedef __attribute__((ext_vector_type(8))) short bf16x8;
typedef __attribute__((ext_vector_type(4))) float f32x4;

static __device__ __forceinline__ unsigned short f2bf(float f) {
    __hip_bfloat16 h = __float2bfloat16(f);   // RNE
    return *reinterpret_cast<unsigned short*>(&h);
}

static __device__ __forceinline__ bf16x8 pack8(float4 lo, float4 hi) {
    union { bf16x8 v; unsigned short u[8]; } t;
    t.u[0] = f2bf(lo.x); t.u[1] = f2bf(lo.y); t.u[2] = f2bf(lo.z); t.u[3] = f2bf(lo.w);
    t.u[4] = f2bf(hi.x); t.u[5] = f2bf(hi.y); t.u[6] = f2bf(hi.z); t.u[7] = f2bf(hi.w);
    return t.v;
}

static __device__ __forceinline__ void gll16(const void* g, void* l) {
    __builtin_amdgcn_global_load_lds(
        (const __attribute__((address_space(1))) unsigned int*)g,
        (__attribute__((address_space(3))) unsigned int*)l,
        16, 0, 0);
}

// ---------------------------------------------------------------------------
// Merged aux kernel: blocks 0-127 wcvt (W -> bf16 K-major Wb), block 128 scan
// (mask -> vidx/nv), blocks 129-192 zero (part + invalid hidden rows).
// All independent; gemm/score follow in stream order.
// ---------------------------------------------------------------------------
__global__ __launch_bounds__(1024) void rfg13_aux(
    const float* __restrict__ W, unsigned short* __restrict__ Wb,
    const unsigned char* __restrict__ msk,
    int* __restrict__ vidx, int* __restrict__ nv_out,
    float* __restrict__ hid, float* __restrict__ part)
{
    __shared__ int Wt[16];
    __shared__ int Wbase[16];
    const int b   = blockIdx.x;
    const int tid = threadIdx.x;

    if (b < 128) {
        // ---- wcvt: W row-major f32 -> Wb[(k>>3)*512 + r][8] bf16 ----
        const int i  = b * 1024 + tid;       // 0..131071
        const int r  = i >> 8;               // 0..511
        const int k8 = i & 255;              // 0..255
        const float* src = W + (size_t)r * H_DIM + k8 * 8;
        float4 a = *reinterpret_cast<const float4*>(src);
        float4 c = *reinterpret_cast<const float4*>(src + 4);
        *reinterpret_cast<bf16x8*>(Wb + ((size_t)k8 * R_DIM + r) * 8) = pack8(a, c);
    } else if (b == 128) {
        // ---- scan: vidx[0..nv) = valid token ids, padded to mult of 64 ----
        const int lane = tid & 63;
        const int wv   = tid >> 6;
        union { uint4 v; unsigned char c[16]; } u;
        u.v = *reinterpret_cast<const uint4*>(msk + tid * 16);
        const unsigned int s4 = u.v.x + u.v.y + u.v.z + u.v.w;  // bytes<=4
        const int cnt = (s4 & 0xFF) + ((s4 >> 8) & 0xFF)
                      + ((s4 >> 16) & 0xFF) + (s4 >> 24);
        int pfx = cnt;
        #pragma unroll
        for (int off = 1; off < 64; off <<= 1) {
            const int t = __shfl_up(pfx, off, 64);
            if (lane >= off) pfx += t;
        }
        if (lane == 63) Wt[wv] = pfx;
        __syncthreads();
        if (tid == 0) {
            int run = 0;
            for (int i = 0; i < 16; ++i) { Wbase[i] = run; run += Wt[i]; }
        }
        __syncthreads();
        int p = Wbase[wv] + pfx - cnt;
        #pragma unroll
        for (int j = 0; j < 16; ++j)
            if (u.c[j]) vidx[p++] = tid * 16 + j;
        if (tid == 1023) {
            const int total = Wbase[15] + Wt[15];
            nv_out[0] = total;
            const int pe = (total + 63) & ~63;
            for (int i = total; i < pe; ++i) vidx[i] = 0;
        }
    } else {
        // ---- zero: part[] and invalid hidden rows ----
        const int zb = b - 129;              // 0..63
        part[zb * 1024 + tid] = 0.0f;        // 64*1024 = 4*NTOK
        const float4 z = make_float4(0.f, 0.f, 0.f, 0.f);
        #pragma unroll 4
        for (int tt = 0; tt < 32; ++tt) {
            const int t = zb * 256 + tt * 8 + (tid >> 7);
            if (!msk[t])
                *reinterpret_cast<float4*>(
                    &hid[(size_t)t * R_DIM + (tid & 127) * 4]) = z;
        }
    }
}

// ---------------------------------------------------------------------------
// Compacted GEMM 64x128, BK=64, 256 thr / 4 waves (2x2 of 32x64), acc[2][4],
// 16 MFMA/wave/step, 32 steps, dbuf + __syncthreads. A rows gathered via
// vidx; f32 in LDS [row][16 chunk], source-swizzled chunk^(row&7). B bf16
// K-major [k8][col][8]. C/partials scattered via vidx.
// ---------------------------------------------------------------------------
__global__ __launch_bounds__(256, 2) void rfg13_gemm(
    const float* __restrict__ x,
    const unsigned short* __restrict__ Wb,
    const int* __restrict__ vidx,
    const int* __restrict__ nvp,
    float* __restrict__ part,            // [4][NTOK] sumsq partials
    float* __restrict__ hid)
{
    __shared__ __align__(16) float4 As[2][1024];    // [buf][row*16+chunk] 32 KiB
    __shared__ __align__(16) short  Bs[2][1024][8]; // [buf][k8*128+col]   32 KiB
    __shared__ float Ps[2][BM];
    __shared__ int   Vr[BM];
    __shared__ int   Vv[BM];

    const int nv  = nvp[0];
    const int tid = threadIdx.x;
    // XCD swizzle: 4 n-tiles of an m-panel -> same XCD.
    const int bid   = blockIdx.x;            // 1024 blocks
    const int xcd   = bid & 7;
    const int local = bid >> 3;              // 0..127
    const int nt    = local & 3;
    const int mt    = (local >> 2) * 8 + xcd;  // bijective 0..255
    const int m0    = mt * BM;
    if (m0 >= nv) return;
    const int n0    = nt * BN;

    const int w  = tid >> 6;
    const int l  = tid & 63;
    const int wr = w >> 1;               // 0..1: 32-row group
    const int wc = w & 1;                // 0..1: 64-col group
    const int fr = l & 15;
    const int fg = l >> 4;               // k-subgroup 0..3

    // A staging rows for this thread: chunk idx = j*256+tid -> row idx>>4
    int vrj[4];
    #pragma unroll
    for (int j = 0; j < 4; ++j)
        vrj[j] = vidx[m0 + (tid >> 4) + 16 * j];

    f32x4 acc[2][4] = {};

#define RFG13_STAGE(ks_, buf_) do {                                      \
        const int _kA = (ks_) * BK;                                      \
        _Pragma("unroll")                                                \
        for (int j = 0; j < 4; ++j) {                                    \
            const int idx = j * 256 + tid;                               \
            const int row = idx >> 4, cL = idx & 15;                     \
            const int cG  = cL ^ (row & 7);                              \
            gll16(x + (size_t)vrj[j] * H_DIM + _kA + cG * 4,             \
                  (char*)&As[buf_][0] + idx * 16);                       \
        }                                                                \
        _Pragma("unroll")                                                \
        for (int j = 0; j < 4; ++j) {                                    \
            const int idx = j * 256 + tid;                               \
            const int k8 = idx >> 7, col = idx & 127;                    \
            gll16(Wb + ((size_t)((ks_) * 8 + k8) * R_DIM + n0 + col) * 8,\
                  (char*)&Bs[buf_][0][0] + idx * 16);                    \
        }                                                                \
    } while (0)

    RFG13_STAGE(0, 0);
    if (tid < BM) {
        Vr[tid] = vidx[m0 + tid];
        Vv[tid] = (m0 + tid) < nv;
    }
    __syncthreads();

    for (int ks = 0; ks < KST; ++ks) {
        const int buf = ks & 1;
        if (ks + 1 < KST) RFG13_STAGE(ks + 1, buf ^ 1);

        bf16x8 bfr[2][4];
        #pragma unroll
        for (int kk = 0; kk < 2; ++kk)
            #pragma unroll
            for (int ni = 0; ni < 4; ++ni)
                bfr[kk][ni] = *reinterpret_cast<const bf16x8*>(
                    &Bs[buf][(kk * 4 + fg) * 128 + wc * 64 + ni * 16 + fr][0]);

        bf16x8 afr[2][2];
        #pragma unroll
        for (int mi = 0; mi < 2; ++mi) {
            const int row = wr * 32 + mi * 16 + fr;
            const int s   = row & 7;
            #pragma unroll
            for (int kk = 0; kk < 2; ++kk) {
                const int g0 = kk * 8 + 2 * fg;
                float4 lo = As[buf][row * 16 + (g0 ^ s)];
                float4 hi = As[buf][row * 16 + ((g0 + 1) ^ s)];
                afr[mi][kk] = pack8(lo, hi);
            }
        }

        #pragma unroll
        for (int kk = 0; kk < 2; ++kk)
            #pragma unroll
            for (int mi = 0; mi < 2; ++mi)
                #pragma unroll
                for (int ni = 0; ni < 4; ++ni)
                    acc[mi][ni] = __builtin_amdgcn_mfma_f32_16x16x32_bf16(
                        afr[mi][kk], bfr[kk][ni], acc[mi][ni], 0, 0, 0);

        __syncthreads();
    }
#undef RFG13_STAGE

    // ---- epilogue: norm partials, scattered C write ----
    #pragma unroll
    for (int mi = 0; mi < 2; ++mi) {
        #pragma unroll
        for (int r = 0; r < 4; ++r) {
            const int rowl = wr * 32 + mi * 16 + fg * 4 + r;
            float s = 0.0f;
            #pragma unroll
            for (int ni = 0; ni < 4; ++ni) {
                const float v = acc[mi][ni][r];
                s = fmaf(v, v, s);
            }
            #pragma unroll
            for (int off = 1; off < 16; off <<= 1)
                s += __shfl_xor(s, off, 64);
            if (fr == 0) Ps[wc][rowl] = s;
        }
    }

    #pragma unroll
    for (int mi = 0; mi < 2; ++mi)
        #pragma unroll
        for (int ni = 0; ni < 4; ++ni)
            #pragma unroll
            for (int r = 0; r < 4; ++r) {
                const int rowl = wr * 32 + mi * 16 + fg * 4 + r;
                if (Vv[rowl])
                    hid[(size_t)Vr[rowl] * R_DIM + n0 + wc * 64 + ni * 16 + fr] =
                        acc[mi][ni][r];
            }

    __syncthreads();
    if (tid < BM && Vv[tid])
        part[(size_t)nt * NTOK + Vr[tid]] = Ps[0][tid] + Ps[1][tid];
}

// ---------------------------------------------------------------------------
// Finish: sum the 4 n-tile partials, sqrt/scale/bias, gate.
// ---------------------------------------------------------------------------
__global__ __launch_bounds__(256) void rfg13_score(
    const unsigned char* __restrict__ msk,
    const float* __restrict__ gsc,
    const float* __restrict__ gbi,
    const float* __restrict__ part,
    float* __restrict__ om,
    float* __restrict__ os)
{
    const int t = blockIdx.x * 256 + threadIdx.x;
    const float s = part[t] + part[NTOK + t] + part[2 * NTOK + t] + part[3 * NTOK + t];
    float sc = sqrtf(s) * gsc[0] - gbi[0];
    if (!(sc > -1.0e30f && sc < 1.0e30f)) sc = 0.0f;  // never emit inf/nan
    const bool keep = (msk[t] != 0) && (sc >= 0.5f);
    om[t] = keep ? 1.0f : 0.0f;
    os[t] = keep ? sc : NEG_BIG;
}

extern "C" void kernel_launch(void* const* d_in, const int* in_sizes, int n_in,
                              void* d_out, int out_size, void* d_ws, size_t ws_size,
                              hipStream_t stream)
{
    const float*         x     = (const float*)d_in[0];
    const unsigned char* msk   = (const unsigned char*)d_in[1];  // jax bool = 1B
    const float*         W     = (const float*)d_in[2];
    const float*         scale = (const float*)d_in[3];
    const float*         bias  = (const float*)d_in[4];

    float* out = (float*)d_out;
    float* om  = out;               // [NTOK]
    float* os  = out + NTOK;        // [NTOK]
    float* hid = out + 2 * NTOK;    // [NTOK][R_DIM]

    char* ws = (char*)d_ws;
    unsigned short* Wb   = (unsigned short*)ws;                       // 2 MiB
    float*          part = (float*)(ws + 2 * 1024 * 1024);            // 256 KiB
    int*            vidx = (int*)(ws + 2 * 1024 * 1024 + 256 * 1024); // 64 KiB
    int*            nvp  = (int*)(ws + 2 * 1024 * 1024 + 320 * 1024); // 4 B

    rfg13_aux<<<193, 1024, 0, stream>>>(W, Wb, msk, vidx, nvp, hid, part);
    rfg13_gemm<<<(NTOK / BM) * (R_DIM / BN), 256, 0, stream>>>(
        x, Wb, vidx, nvp, part, hid);
    rfg13_score<<<NTOK / 256, 256, 0, stream>>>(msk, scale, bias, part, om, os);
}

// Round 14
// 44.851 us; speedup vs baseline: 4.1094x; 1.2508x over previous
//
// RoutingFreeGate — v14: v13 + counted-vmcnt 2-barrier K-loop (m201 skeleton,
// lookahead=2 on the SAME double buffer: stage k+2 after the reads-done
// barrier). Per step: vmcnt(8) -> s_barrier -> ds_read/pack -> lgkmcnt(0) ->
// s_barrier -> stage(k+2) -> 16 MFMA. Invariant: newest 8 VMEM = stage(k+1),
// so vmcnt(8) == "stage(k) complete", no drain. Geometry/epilogue = v13.
#include <hip/hip_runtime.h>
#include <hip/hip_bf16.h>
#include <math.h>

#define H_DIM 2048
#define R_DIM 512
#define NTOK  16384
#define BM    64
#define BN    128
#define BK    64
#define KST   (H_DIM / BK)           // 32
#define NEG_BIG (-1.0e30f)           // finite in f32 AND after bf16 rounding

typedef __attribute__((ext_vector_type(8))) short bf16x8;
typedef __attribute__((ext_vector_type(4))) float f32x4;

static __device__ __forceinline__ unsigned short f2bf(float f) {
    __hip_bfloat16 h = __float2bfloat16(f);   // RNE
    return *reinterpret_cast<unsigned short*>(&h);
}

static __device__ __forceinline__ bf16x8 pack8(float4 lo, float4 hi) {
    union { bf16x8 v; unsigned short u[8]; } t;
    t.u[0] = f2bf(lo.x); t.u[1] = f2bf(lo.y); t.u[2] = f2bf(lo.z); t.u[3] = f2bf(lo.w);
    t.u[4] = f2bf(hi.x); t.u[5] = f2bf(hi.y); t.u[6] = f2bf(hi.z); t.u[7] = f2bf(hi.w);
    return t.v;
}

static __device__ __forceinline__ void gll16(const void* g, void* l) {
    __builtin_amdgcn_global_load_lds(
        (const __attribute__((address_space(1))) unsigned int*)g,
        (__attribute__((address_space(3))) unsigned int*)l,
        16, 0, 0);
}

// ---------------------------------------------------------------------------
// Merged aux kernel: blocks 0-127 wcvt (W -> bf16 K-major Wb), block 128 scan
// (mask -> vidx/nv), blocks 129-192 zero (part + invalid hidden rows).
// ---------------------------------------------------------------------------
__global__ __launch_bounds__(1024) void rfg14_aux(
    const float* __restrict__ W, unsigned short* __restrict__ Wb,
    const unsigned char* __restrict__ msk,
    int* __restrict__ vidx, int* __restrict__ nv_out,
    float* __restrict__ hid, float* __restrict__ part)
{
    __shared__ int Wt[16];
    __shared__ int Wbase[16];
    const int b   = blockIdx.x;
    const int tid = threadIdx.x;

    if (b < 128) {
        const int i  = b * 1024 + tid;       // 0..131071
        const int r  = i >> 8;               // 0..511
        const int k8 = i & 255;              // 0..255
        const float* src = W + (size_t)r * H_DIM + k8 * 8;
        float4 a = *reinterpret_cast<const float4*>(src);
        float4 c = *reinterpret_cast<const float4*>(src + 4);
        *reinterpret_cast<bf16x8*>(Wb + ((size_t)k8 * R_DIM + r) * 8) = pack8(a, c);
    } else if (b == 128) {
        const int lane = tid & 63;
        const int wv   = tid >> 6;
        union { uint4 v; unsigned char c[16]; } u;
        u.v = *reinterpret_cast<const uint4*>(msk + tid * 16);
        const unsigned int s4 = u.v.x + u.v.y + u.v.z + u.v.w;  // bytes<=4
        const int cnt = (s4 & 0xFF) + ((s4 >> 8) & 0xFF)
                      + ((s4 >> 16) & 0xFF) + (s4 >> 24);
        int pfx = cnt;
        #pragma unroll
        for (int off = 1; off < 64; off <<= 1) {
            const int t = __shfl_up(pfx, off, 64);
            if (lane >= off) pfx += t;
        }
        if (lane == 63) Wt[wv] = pfx;
        __syncthreads();
        if (tid == 0) {
            int run = 0;
            for (int i = 0; i < 16; ++i) { Wbase[i] = run; run += Wt[i]; }
        }
        __syncthreads();
        int p = Wbase[wv] + pfx - cnt;
        #pragma unroll
        for (int j = 0; j < 16; ++j)
            if (u.c[j]) vidx[p++] = tid * 16 + j;
        if (tid == 1023) {
            const int total = Wbase[15] + Wt[15];
            nv_out[0] = total;
            const int pe = (total + 63) & ~63;
            for (int i = total; i < pe; ++i) vidx[i] = 0;
        }
    } else {
        const int zb = b - 129;              // 0..63
        part[zb * 1024 + tid] = 0.0f;        // 64*1024 = 4*NTOK
        const float4 z = make_float4(0.f, 0.f, 0.f, 0.f);
        #pragma unroll 4
        for (int tt = 0; tt < 32; ++tt) {
            const int t = zb * 256 + tt * 8 + (tid >> 7);
            if (!msk[t])
                *reinterpret_cast<float4*>(
                    &hid[(size_t)t * R_DIM + (tid & 127) * 4]) = z;
        }
    }
}

// ---------------------------------------------------------------------------
// Compacted GEMM 64x128, BK=64, 256 thr / 4 waves (2x2 of 32x64), acc[2][4],
// counted-vmcnt 2-barrier loop, lookahead-2 on a double buffer.
// ---------------------------------------------------------------------------
__global__ __launch_bounds__(256, 2) void rfg14_gemm(
    const float* __restrict__ x,
    const unsigned short* __restrict__ Wb,
    const int* __restrict__ vidx,
    const int* __restrict__ nvp,
    float* __restrict__ part,            // [4][NTOK] sumsq partials
    float* __restrict__ hid)
{
    __shared__ __align__(16) float4 As[2][1024];    // [buf][row*16+chunk] 32 KiB
    __shared__ __align__(16) short  Bs[2][1024][8]; // [buf][k8*128+col]   32 KiB
    __shared__ float Ps[2][BM];
    __shared__ int   Vr[BM];
    __shared__ int   Vv[BM];

    const int nv  = nvp[0];
    const int tid = threadIdx.x;
    // XCD swizzle: 4 n-tiles of an m-panel -> same XCD.
    const int bid   = blockIdx.x;            // 1024 blocks
    const int xcd   = bid & 7;
    const int local = bid >> 3;              // 0..127
    const int nt    = local & 3;
    const int mt    = (local >> 2) * 8 + xcd;  // bijective 0..255
    const int m0    = mt * BM;
    if (m0 >= nv) return;
    const int n0    = nt * BN;

    const int w  = tid >> 6;
    const int l  = tid & 63;
    const int wr = w >> 1;               // 0..1: 32-row group
    const int wc = w & 1;                // 0..1: 64-col group
    const int fr = l & 15;
    const int fg = l >> 4;               // k-subgroup 0..3

    // vidx gathers issued BEFORE the stages so the VMEM-queue invariant
    // "newest 8 ops == stage(ks+1)" holds at every loop iteration.
    int vrj[4];
    #pragma unroll
    for (int j = 0; j < 4; ++j)
        vrj[j] = vidx[m0 + (tid >> 4) + 16 * j];
    if (tid < BM) {
        Vr[tid] = vidx[m0 + tid];
        Vv[tid] = (m0 + tid) < nv;
    }

    f32x4 acc[2][4] = {};

#define RFG14_STAGE(ks_, buf_) do {                                      \
        const int _kA = (ks_) * BK;                                      \
        _Pragma("unroll")                                                \
        for (int j = 0; j < 4; ++j) {                                    \
            const int idx = j * 256 + tid;                               \
            const int row = idx >> 4, cL = idx & 15;                     \
            const int cG  = cL ^ (row & 7);                              \
            gll16(x + (size_t)vrj[j] * H_DIM + _kA + cG * 4,             \
                  (char*)&As[buf_][0] + idx * 16);                       \
        }                                                                \
        _Pragma("unroll")                                                \
        for (int j = 0; j < 4; ++j) {                                    \
            const int idx = j * 256 + tid;                               \
            const int k8 = idx >> 7, col = idx & 127;                    \
            gll16(Wb + ((size_t)((ks_) * 8 + k8) * R_DIM + n0 + col) * 8,\
                  (char*)&Bs[buf_][0][0] + idx * 16);                    \
        }                                                                \
    } while (0)

    // Phase body: READS(buf) -> lgkm0 -> barrier -> STAGE(ks+2 -> buf) -> MFMA
#define RFG14_BODY(ks_, buf_, stage_)  do {                              \
        bf16x8 bfr[2][4];                                                \
        _Pragma("unroll")                                                \
        for (int kk = 0; kk < 2; ++kk)                                   \
            _Pragma("unroll")                                            \
            for (int ni = 0; ni < 4; ++ni)                               \
                bfr[kk][ni] = *reinterpret_cast<const bf16x8*>(          \
                    &Bs[buf_][(kk * 4 + fg) * 128 + wc * 64 + ni * 16 + fr][0]); \
        bf16x8 afr[2][2];                                                \
        _Pragma("unroll")                                                \
        for (int mi = 0; mi < 2; ++mi) {                                 \
            const int row = wr * 32 + mi * 16 + fr;                      \
            const int s   = row & 7;                                     \
            _Pragma("unroll")                                            \
            for (int kk = 0; kk < 2; ++kk) {                             \
                const int g0 = kk * 8 + 2 * fg;                          \
                float4 lo = As[buf_][row * 16 + (g0 ^ s)];               \
                float4 hi = As[buf_][row * 16 + ((g0 + 1) ^ s)];         \
                afr[mi][kk] = pack8(lo, hi);                             \
            }                                                            \
        }                                                                \
        asm volatile("s_waitcnt lgkmcnt(0)" ::: "memory");               \
        __builtin_amdgcn_s_barrier();      /* all waves done reading buf */ \
        if (stage_) RFG14_STAGE((ks_) + 2, buf_);                        \
        __builtin_amdgcn_s_setprio(1);                                   \
        _Pragma("unroll")                                                \
        for (int kk = 0; kk < 2; ++kk)                                   \
            _Pragma("unroll")                                            \
            for (int mi = 0; mi < 2; ++mi)                               \
                _Pragma("unroll")                                        \
                for (int ni = 0; ni < 4; ++ni)                           \
                    acc[mi][ni] = __builtin_amdgcn_mfma_f32_16x16x32_bf16(\
                        afr[mi][kk], bfr[kk][ni], acc[mi][ni], 0, 0, 0); \
        __builtin_amdgcn_s_setprio(0);                                   \
    } while (0)

    RFG14_STAGE(0, 0);
    RFG14_STAGE(1, 1);

    for (int ks = 0; ks < KST - 2; ++ks) {       // 0..29: stage ks+2
        asm volatile("s_waitcnt vmcnt(8)" ::: "memory");  // stage(ks) done
        __builtin_amdgcn_s_barrier();
        RFG14_BODY(ks, (ks & 1), true);
    }
    {   // ks = KST-2: no stage
        asm volatile("s_waitcnt vmcnt(8)" ::: "memory");
        __builtin_amdgcn_s_barrier();
        RFG14_BODY(KST - 2, ((KST - 2) & 1), false);
    }
    {   // ks = KST-1: drain
        asm volatile("s_waitcnt vmcnt(0)" ::: "memory");
        __builtin_amdgcn_s_barrier();
        RFG14_BODY(KST - 1, ((KST - 1) & 1), false);
    }
#undef RFG14_BODY
#undef RFG14_STAGE

    // ---- epilogue: norm partials, scattered C write ----
    #pragma unroll
    for (int mi = 0; mi < 2; ++mi) {
        #pragma unroll
        for (int r = 0; r < 4; ++r) {
            const int rowl = wr * 32 + mi * 16 + fg * 4 + r;
            float s = 0.0f;
            #pragma unroll
            for (int ni = 0; ni < 4; ++ni) {
                const float v = acc[mi][ni][r];
                s = fmaf(v, v, s);
            }
            #pragma unroll
            for (int off = 1; off < 16; off <<= 1)
                s += __shfl_xor(s, off, 64);
            if (fr == 0) Ps[wc][rowl] = s;
        }
    }

    #pragma unroll
    for (int mi = 0; mi < 2; ++mi)
        #pragma unroll
        for (int ni = 0; ni < 4; ++ni)
            #pragma unroll
            for (int r = 0; r < 4; ++r) {
                const int rowl = wr * 32 + mi * 16 + fg * 4 + r;
                if (Vv[rowl])
                    hid[(size_t)Vr[rowl] * R_DIM + n0 + wc * 64 + ni * 16 + fr] =
                        acc[mi][ni][r];
            }

    __syncthreads();
    if (tid < BM && Vv[tid])
        part[(size_t)nt * NTOK + Vr[tid]] = Ps[0][tid] + Ps[1][tid];
}

// ---------------------------------------------------------------------------
// Finish: sum the 4 n-tile partials, sqrt/scale/bias, gate.
// ---------------------------------------------------------------------------
__global__ __launch_bounds__(256) void rfg14_score(
    const unsigned char* __restrict__ msk,
    const float* __restrict__ gsc,
    const float* __restrict__ gbi,
    const float* __restrict__ part,
    float* __restrict__ om,
    float* __restrict__ os)
{
    const int t = blockIdx.x * 256 + threadIdx.x;
    const float s = part[t] + part[NTOK + t] + part[2 * NTOK + t] + part[3 * NTOK + t];
    float sc = sqrtf(s) * gsc[0] - gbi[0];
    if (!(sc > -1.0e30f && sc < 1.0e30f)) sc = 0.0f;  // never emit inf/nan
    const bool keep = (msk[t] != 0) && (sc >= 0.5f);
    om[t] = keep ? 1.0f : 0.0f;
    os[t] = keep ? sc : NEG_BIG;
}

extern "C" void kernel_launch(void* const* d_in, const int* in_sizes, int n_in,
                              void* d_out, int out_size, void* d_ws, size_t ws_size,
                              hipStream_t stream)
{
    const float*         x     = (const float*)d_in[0];
    const unsigned char* msk   = (const unsigned char*)d_in[1];  // jax bool = 1B
    const float*         W     = (const float*)d_in[2];
    const float*         scale = (const float*)d_in[3];
    const float*         bias  = (const float*)d_in[4];

    float* out = (float*)d_out;
    float* om  = out;               // [NTOK]
    float* os  = out + NTOK;        // [NTOK]
    float* hid = out + 2 * NTOK;    // [NTOK][R_DIM]

    char* ws = (char*)d_ws;
    unsigned short* Wb   = (unsigned short*)ws;                       // 2 MiB
    float*          part = (float*)(ws + 2 * 1024 * 1024);            // 256 KiB
    int*            vidx = (int*)(ws + 2 * 1024 * 1024 + 256 * 1024); // 64 KiB
    int*            nvp  = (int*)(ws + 2 * 1024 * 1024 + 320 * 1024); // 4 B

    rfg14_aux<<<193, 1024, 0, stream>>>(W, Wb, msk, vidx, nvp, hid, part);
    rfg14_gemm<<<(NTOK / BM) * (R_DIM / BN), 256, 0, stream>>>(
        x, Wb, vidx, nvp, part, hid);
    rfg14_score<<<NTOK / 256, 256, 0, stream>>>(msk, scale, bias, part, om, os);
}

// Round 15
// 40.349 us; speedup vs baseline: 4.5679x; 1.1116x over previous
//
// RoutingFreeGate — v15: v14 + (a) invalid-row hid zeroing moved into gemm's
// inactive blocks (overlaps compute; was a serial aux leg), (b) part[] zeroing
// dropped (score's nan-clamp + mask gate make unwritten slots harmless),
// (c) aux = wcvt + scan only (129 blocks). Gemm hot loop identical to v14.
#include <hip/hip_runtime.h>
#include <hip/hip_bf16.h>
#include <math.h>

#define H_DIM 2048
#define R_DIM 512
#define NTOK  16384
#define BM    64
#define BN    128
#define BK    64
#define KST   (H_DIM / BK)           // 32
#define NEG_BIG (-1.0e30f)           // finite in f32 AND after bf16 rounding

typedef __attribute__((ext_vector_type(8))) short bf16x8;
typedef __attribute__((ext_vector_type(4))) float f32x4;

static __device__ __forceinline__ unsigned short f2bf(float f) {
    __hip_bfloat16 h = __float2bfloat16(f);   // RNE
    return *reinterpret_cast<unsigned short*>(&h);
}

static __device__ __forceinline__ bf16x8 pack8(float4 lo, float4 hi) {
    union { bf16x8 v; unsigned short u[8]; } t;
    t.u[0] = f2bf(lo.x); t.u[1] = f2bf(lo.y); t.u[2] = f2bf(lo.z); t.u[3] = f2bf(lo.w);
    t.u[4] = f2bf(hi.x); t.u[5] = f2bf(hi.y); t.u[6] = f2bf(hi.z); t.u[7] = f2bf(hi.w);
    return t.v;
}

static __device__ __forceinline__ void gll16(const void* g, void* l) {
    __builtin_amdgcn_global_load_lds(
        (const __attribute__((address_space(1))) unsigned int*)g,
        (__attribute__((address_space(3))) unsigned int*)l,
        16, 0, 0);
}

// ---------------------------------------------------------------------------
// Aux: blocks 0-127 wcvt (W -> bf16 K-major Wb), block 128 scan (mask ->
// vidx/nv). Invalid-row zeroing now lives in the gemm's inactive blocks.
// ---------------------------------------------------------------------------
__global__ __launch_bounds__(1024) void rfg15_aux(
    const float* __restrict__ W, unsigned short* __restrict__ Wb,
    const unsigned char* __restrict__ msk,
    int* __restrict__ vidx, int* __restrict__ nv_out)
{
    __shared__ int Wt[16];
    __shared__ int Wbase[16];
    const int b   = blockIdx.x;
    const int tid = threadIdx.x;

    if (b < 128) {
        const int i  = b * 1024 + tid;       // 0..131071
        const int r  = i >> 8;               // 0..511
        const int k8 = i & 255;              // 0..255
        const float* src = W + (size_t)r * H_DIM + k8 * 8;
        float4 a = *reinterpret_cast<const float4*>(src);
        float4 c = *reinterpret_cast<const float4*>(src + 4);
        *reinterpret_cast<bf16x8*>(Wb + ((size_t)k8 * R_DIM + r) * 8) = pack8(a, c);
    } else {
        const int lane = tid & 63;
        const int wv   = tid >> 6;
        union { uint4 v; unsigned char c[16]; } u;
        u.v = *reinterpret_cast<const uint4*>(msk + tid * 16);
        const unsigned int s4 = u.v.x + u.v.y + u.v.z + u.v.w;  // bytes<=4
        const int cnt = (s4 & 0xFF) + ((s4 >> 8) & 0xFF)
                      + ((s4 >> 16) & 0xFF) + (s4 >> 24);
        int pfx = cnt;
        #pragma unroll
        for (int off = 1; off < 64; off <<= 1) {
            const int t = __shfl_up(pfx, off, 64);
            if (lane >= off) pfx += t;
        }
        if (lane == 63) Wt[wv] = pfx;
        __syncthreads();
        if (tid == 0) {
            int run = 0;
            for (int i = 0; i < 16; ++i) { Wbase[i] = run; run += Wt[i]; }
        }
        __syncthreads();
        int p = Wbase[wv] + pfx - cnt;
        #pragma unroll
        for (int j = 0; j < 16; ++j)
            if (u.c[j]) vidx[p++] = tid * 16 + j;
        if (tid == 1023) {
            const int total = Wbase[15] + Wt[15];
            nv_out[0] = total;
            const int pe = (total + 63) & ~63;
            for (int i = total; i < pe; ++i) vidx[i] = 0;
        }
    }
}

// ---------------------------------------------------------------------------
// Compacted GEMM 64x128, BK=64, 256 thr / 4 waves (2x2 of 32x64), acc[2][4],
// counted-vmcnt 2-barrier loop, lookahead-2 (v14 loop, unchanged). Inactive
// blocks (m0 >= nv) grid-stride the token space zeroing invalid hidden rows.
// ---------------------------------------------------------------------------
__global__ __launch_bounds__(256, 2) void rfg15_gemm(
    const float* __restrict__ x,
    const unsigned char* __restrict__ msk,
    const unsigned short* __restrict__ Wb,
    const int* __restrict__ vidx,
    const int* __restrict__ nvp,
    float* __restrict__ part,            // [4][NTOK] sumsq partials
    float* __restrict__ hid)
{
    __shared__ __align__(16) float4 As[2][1024];    // [buf][row*16+chunk] 32 KiB
    __shared__ __align__(16) short  Bs[2][1024][8]; // [buf][k8*128+col]   32 KiB
    __shared__ float Ps[2][BM];
    __shared__ int   Vr[BM];
    __shared__ int   Vv[BM];

    const int nv  = nvp[0];
    const int tid = threadIdx.x;
    // XCD swizzle: 4 n-tiles of an m-panel -> same XCD.
    const int bid   = blockIdx.x;            // 1024 blocks
    const int xcd   = bid & 7;
    const int local = bid >> 3;              // 0..127
    const int nt    = local & 3;
    const int mt    = (local >> 2) * 8 + xcd;  // bijective 0..255
    const int m0    = mt * BM;

    if (m0 >= nv) {
        // ---- inactive block: zero invalid hidden rows (grid-stride) ----
        const int mt_min = (nv + 63) >> 6;
        const int Z = (256 - mt_min) * 4;            // # inactive blocks
        const int z = (mt - mt_min) * 4 + nt;        // ordinal in [0, Z)
        const float2 z2 = make_float2(0.f, 0.f);
        for (int t = z; t < NTOK; t += Z)
            if (!msk[t])
                *reinterpret_cast<float2*>(&hid[(size_t)t * R_DIM + tid * 2]) = z2;
        return;
    }
    const int n0 = nt * BN;

    const int w  = tid >> 6;
    const int l  = tid & 63;
    const int wr = w >> 1;               // 0..1: 32-row group
    const int wc = w & 1;                // 0..1: 64-col group
    const int fr = l & 15;
    const int fg = l >> 4;               // k-subgroup 0..3

    // vidx gathers issued BEFORE the stages (oldest in VMEM queue) so the
    // invariant "newest 8 ops == stage(ks+1)" holds at every vmcnt(8).
    int vrj[4];
    #pragma unroll
    for (int j = 0; j < 4; ++j)
        vrj[j] = vidx[m0 + (tid >> 4) + 16 * j];
    if (tid < BM) {
        Vr[tid] = vidx[m0 + tid];
        Vv[tid] = (m0 + tid) < nv;
    }

    f32x4 acc[2][4] = {};

#define RFG15_STAGE(ks_, buf_) do {                                      \
        const int _kA = (ks_) * BK;                                      \
        _Pragma("unroll")                                                \
        for (int j = 0; j < 4; ++j) {                                    \
            const int idx = j * 256 + tid;                               \
            const int row = idx >> 4, cL = idx & 15;                     \
            const int cG  = cL ^ (row & 7);                              \
            gll16(x + (size_t)vrj[j] * H_DIM + _kA + cG * 4,             \
                  (char*)&As[buf_][0] + idx * 16);                       \
        }                                                                \
        _Pragma("unroll")                                                \
        for (int j = 0; j < 4; ++j) {                                    \
            const int idx = j * 256 + tid;                               \
            const int k8 = idx >> 7, col = idx & 127;                    \
            gll16(Wb + ((size_t)((ks_) * 8 + k8) * R_DIM + n0 + col) * 8,\
                  (char*)&Bs[buf_][0][0] + idx * 16);                    \
        }                                                                \
    } while (0)

    // Phase body: READS(buf) -> lgkm0 -> barrier -> STAGE(ks+2 -> buf) -> MFMA
#define RFG15_BODY(ks_, buf_, stage_)  do {                              \
        bf16x8 bfr[2][4];                                                \
        _Pragma("unroll")                                                \
        for (int kk = 0; kk < 2; ++kk)                                   \
            _Pragma("unroll")                                            \
            for (int ni = 0; ni < 4; ++ni)                               \
                bfr[kk][ni] = *reinterpret_cast<const bf16x8*>(          \
                    &Bs[buf_][(kk * 4 + fg) * 128 + wc * 64 + ni * 16 + fr][0]); \
        bf16x8 afr[2][2];                                                \
        _Pragma("unroll")                                                \
        for (int mi = 0; mi < 2; ++mi) {                                 \
            const int row = wr * 32 + mi * 16 + fr;                      \
            const int s   = row & 7;                                     \
            _Pragma("unroll")                                            \
            for (int kk = 0; kk < 2; ++kk) {                             \
                const int g0 = kk * 8 + 2 * fg;                          \
                float4 lo = As[buf_][row * 16 + (g0 ^ s)];               \
                float4 hi = As[buf_][row * 16 + ((g0 + 1) ^ s)];         \
                afr[mi][kk] = pack8(lo, hi);                             \
            }                                                            \
        }                                                                \
        asm volatile("s_waitcnt lgkmcnt(0)" ::: "memory");               \
        __builtin_amdgcn_s_barrier();      /* all waves done reading buf */ \
        if (stage_) RFG15_STAGE((ks_) + 2, buf_);                        \
        __builtin_amdgcn_s_setprio(1);                                   \
        _Pragma("unroll")                                                \
        for (int kk = 0; kk < 2; ++kk)                                   \
            _Pragma("unroll")                                            \
            for (int mi = 0; mi < 2; ++mi)                               \
                _Pragma("unroll")                                        \
                for (int ni = 0; ni < 4; ++ni)                           \
                    acc[mi][ni] = __builtin_amdgcn_mfma_f32_16x16x32_bf16(\
                        afr[mi][kk], bfr[kk][ni], acc[mi][ni], 0, 0, 0); \
        __builtin_amdgcn_s_setprio(0);                                   \
    } while (0)

    RFG15_STAGE(0, 0);
    RFG15_STAGE(1, 1);

    for (int ks = 0; ks < KST - 2; ++ks) {       // 0..29: stage ks+2
        asm volatile("s_waitcnt vmcnt(8)" ::: "memory");  // stage(ks) done
        __builtin_amdgcn_s_barrier();
        RFG15_BODY(ks, (ks & 1), true);
    }
    {   // ks = KST-2: no stage
        asm volatile("s_waitcnt vmcnt(8)" ::: "memory");
        __builtin_amdgcn_s_barrier();
        RFG15_BODY(KST - 2, ((KST - 2) & 1), false);
    }
    {   // ks = KST-1: drain
        asm volatile("s_waitcnt vmcnt(0)" ::: "memory");
        __builtin_amdgcn_s_barrier();
        RFG15_BODY(KST - 1, ((KST - 1) & 1), false);
    }
#undef RFG15_BODY
#undef RFG15_STAGE

    // ---- epilogue: norm partials, scattered C write ----
    #pragma unroll
    for (int mi = 0; mi < 2; ++mi) {
        #pragma unroll
        for (int r = 0; r < 4; ++r) {
            const int rowl = wr * 32 + mi * 16 + fg * 4 + r;
            float s = 0.0f;
            #pragma unroll
            for (int ni = 0; ni < 4; ++ni) {
                const float v = acc[mi][ni][r];
                s = fmaf(v, v, s);
            }
            #pragma unroll
            for (int off = 1; off < 16; off <<= 1)
                s += __shfl_xor(s, off, 64);
            if (fr == 0) Ps[wc][rowl] = s;
        }
    }

    #pragma unroll
    for (int mi = 0; mi < 2; ++mi)
        #pragma unroll
        for (int ni = 0; ni < 4; ++ni)
            #pragma unroll
            for (int r = 0; r < 4; ++r) {
                const int rowl = wr * 32 + mi * 16 + fg * 4 + r;
                if (Vv[rowl])
                    hid[(size_t)Vr[rowl] * R_DIM + n0 + wc * 64 + ni * 16 + fr] =
                        acc[mi][ni][r];
            }

    __syncthreads();
    if (tid < BM && Vv[tid])
        part[(size_t)nt * NTOK + Vr[tid]] = Ps[0][tid] + Ps[1][tid];
}

// ---------------------------------------------------------------------------
// Finish: sum the 4 n-tile partials, sqrt/scale/bias, gate. Unwritten part
// slots (invalid tokens) may hold garbage: nan-clamp + msk gate handle it.
// ---------------------------------------------------------------------------
__global__ __launch_bounds__(256) void rfg15_score(
    const unsigned char* __restrict__ msk,
    const float* __restrict__ gsc,
    const float* __restrict__ gbi,
    const float* __restrict__ part,
    float* __restrict__ om,
    float* __restrict__ os)
{
    const int t = blockIdx.x * 256 + threadIdx.x;
    const float s = part[t] + part[NTOK + t] + part[2 * NTOK + t] + part[3 * NTOK + t];
    float sc = sqrtf(s) * gsc[0] - gbi[0];
    if (!(sc > -1.0e30f && sc < 1.0e30f)) sc = 0.0f;  // never emit inf/nan
    const bool keep = (msk[t] != 0) && (sc >= 0.5f);
    om[t] = keep ? 1.0f : 0.0f;
    os[t] = keep ? sc : NEG_BIG;
}

extern "C" void kernel_launch(void* const* d_in, const int* in_sizes, int n_in,
                              void* d_out, int out_size, void* d_ws, size_t ws_size,
                              hipStream_t stream)
{
    const float*         x     = (const float*)d_in[0];
    const unsigned char* msk   = (const unsigned char*)d_in[1];  // jax bool = 1B
    const float*         W     = (const float*)d_in[2];
    const float*         scale = (const float*)d_in[3];
    const float*         bias  = (const float*)d_in[4];

    float* out = (float*)d_out;
    float* om  = out;               // [NTOK]
    float* os  = out + NTOK;        // [NTOK]
    float* hid = out + 2 * NTOK;    // [NTOK][R_DIM]

    char* ws = (char*)d_ws;
    unsigned short* Wb   = (unsigned short*)ws;                       // 2 MiB
    float*          part = (float*)(ws + 2 * 1024 * 1024);            // 256 KiB
    int*            vidx = (int*)(ws + 2 * 1024 * 1024 + 256 * 1024); // 64 KiB
    int*            nvp  = (int*)(ws + 2 * 1024 * 1024 + 320 * 1024); // 4 B

    rfg15_aux<<<129, 1024, 0, stream>>>(W, Wb, msk, vidx, nvp);
    rfg15_gemm<<<(NTOK / BM) * (R_DIM / BN), 256, 0, stream>>>(
        x, msk, Wb, vidx, nvp, part, hid);
    rfg15_score<<<NTOK / 256, 256, 0, stream>>>(msk, scale, bias, part, om, os);
}